// Round 10
// baseline (323.079 us; speedup 1.0000x reference)
//
#include <hip/hip_runtime.h>
#include <math.h>

#define NN 50000
#define NE 640000
#define HIDC 128
#define NTILES ((NN + 63)/64)

typedef short  short8 __attribute__((ext_vector_type(8)));
typedef __bf16 bf16x8 __attribute__((ext_vector_type(8)));
typedef float  f32x4  __attribute__((ext_vector_type(4)));
typedef unsigned int uint2v __attribute__((ext_vector_type(2)));
typedef unsigned int uint4v __attribute__((ext_vector_type(4)));

__device__ __forceinline__ unsigned short f2bf(float f) {
    unsigned int b = __float_as_uint(f);
    b += 0x7FFFu + ((b >> 16) & 1u);          // RTNE
    return (unsigned short)(b >> 16);
}
// silu via v_rcp (1 op) instead of IEEE div (~10 ops). ~1ulp, invisible at bf16.
__device__ __forceinline__ float silu_f(float v) {
    return v * __builtin_amdgcn_rcpf(1.0f + __expf(-v));
}
// packed RTNE f32->bf16 pair (1 VALU op)
__device__ __forceinline__ unsigned int cvtpk(float a, float b) {
    unsigned int r;
    asm("v_cvt_pk_bf16_f32 %0, %1, %2" : "=v"(r) : "v"(a), "v"(b));
    return r;
}

// ---------------- merged prep: weight transposes + degree count ----------------
__global__ void convw_count_kernel(const float* __restrict__ Wm1, const float* __restrict__ Wm2,
                                   const float* __restrict__ Wc1, const float* __restrict__ Wn1,
                                   const float* __restrict__ Wn2, const int* __restrict__ ei,
                                   unsigned short* __restrict__ wta, unsigned short* __restrict__ wtb,
                                   unsigned short* __restrict__ wt2, unsigned short* __restrict__ wtc1,
                                   unsigned short* __restrict__ wtn1, unsigned short* __restrict__ wtn2,
                                   int* __restrict__ cnt) {
    if (blockIdx.x >= 448) {   // count part
        const int e = (blockIdx.x - 448) * 256 + threadIdx.x;
        if (e < NE) atomicAdd(&cnt[ei[e]], 1);
        return;
    }
    const int i = blockIdx.x * 256 + threadIdx.x;
    if (i < 16384) {
        const int n = i >> 7, k = i & 127;
        wta[i] = f2bf(Wm1[k * 128 + n]);
    } else if (i < 32768) {
        const int j = i - 16384; const int n = j >> 7, k = j & 127;
        wtb[j] = f2bf(Wm1[(128 + k) * 128 + n]);
    } else if (i < 49152) {
        const int j = i - 32768; const int n = j >> 7, k = j & 127;
        wt2[j] = f2bf(Wm2[k * 128 + n]);
    } else if (i < 65536) {
        const int j = i - 49152; const int n = j >> 7, k = j & 127;
        wtc1[j] = f2bf(Wc1[k * 128 + n]);
    } else if (i < 98304) {
        const int j = i - 65536; const int n = j >> 8, k = j & 255;
        wtn1[j] = f2bf(Wn1[k * 128 + n]);
    } else if (i < 114688) {
        const int j = i - 98304; const int n = j >> 7, k = j & 127;
        wtn2[j] = f2bf(Wn2[k * 128 + n]);
    }
}

// ---------------- fused CSR scan (one block, 1024 threads) ----------------
__global__ void scan_fused_kernel(const int* __restrict__ cnt, int* __restrict__ offs2) {
    __shared__ int wtot[16];
    const int t = threadIdx.x, lane = t & 63, wid = t >> 6;
    const int base = t * 49;                 // 1024*49 = 50176 >= NN
    int s = 0;
    for (int i = 0; i < 49; ++i) { const int idx = base + i; if (idx < NN) s += cnt[idx]; }
    int inc = s;
    #pragma unroll
    for (int d = 1; d < 64; d <<= 1) { int u = __shfl_up(inc, d, 64); if (lane >= d) inc += u; }
    if (lane == 63) wtot[wid] = inc;
    __syncthreads();
    if (t == 0) { int a = 0; for (int w = 0; w < 16; ++w) { int v = wtot[w]; wtot[w] = a; a += v; } }
    __syncthreads();
    int pre = wtot[wid] + inc - s;
    for (int i = 0; i < 49; ++i) {
        const int idx = base + i;
        if (idx < NN) { offs2[idx] = pre; pre += cnt[idx]; }
    }
}

// scatter + edge-data pack: epck[slot] = {dx,dy,dz,dist | ea0,ea1,ea2, src|dst<<16}
__global__ void scatter_kernel(const int* __restrict__ ei, const float* __restrict__ pos,
                               const float* __restrict__ eattr,
                               int* __restrict__ offs2, int4* __restrict__ epck) {
    const int e = blockIdx.x * 256 + threadIdx.x;
    if (e >= NE) return;
    const int s = ei[e], d = ei[NE + e];
    const int slot = atomicAdd(&offs2[s], 1);
    const float dx = pos[s*3+0] - pos[d*3+0];
    const float dy = pos[s*3+1] - pos[d*3+1];
    const float dz = pos[s*3+2] - pos[d*3+2];
    const float dist = sqrtf(dx*dx + dy*dy + dz*dz);
    int4 a, b;
    a.x = __float_as_int(dx); a.y = __float_as_int(dy);
    a.z = __float_as_int(dz); a.w = __float_as_int(dist);
    b.x = __float_as_int(eattr[e*3+0]); b.y = __float_as_int(eattr[e*3+1]);
    b.z = __float_as_int(eattr[e*3+2]); b.w = s | (d << 16);
    epck[(size_t)slot * 2 + 0] = a;
    epck[(size_t)slot * 2 + 1] = b;
}

// ---------------- P/Q precompute + agg/cagg zeroing (fused grid) ----------------
// blocks [0, NTILES): P = x*Wa + bm1, Q = x*Wb.  blocks [NTILES, NTILES+200): zero agg|cagg.
__launch_bounds__(512, 4)
__global__ void pq_kernel(const float* __restrict__ x,
                          const unsigned short* __restrict__ wta,
                          const unsigned short* __restrict__ wtb,
                          const float* __restrict__ bm1v,
                          unsigned short* __restrict__ Pb, unsigned short* __restrict__ Qb,
                          float* __restrict__ aggz)
{
    if (blockIdx.x >= NTILES) {   // zero section: agg (6.4M f32) + cagg (150k f32) contiguous
        const int zt = (blockIdx.x - NTILES) * 512 + threadIdx.x;   // 0..102399
        const f32x4 z4v = {0.f, 0.f, 0.f, 0.f};
        for (size_t i = zt; i < 1637500; i += 102400)
            *reinterpret_cast<f32x4*>(aggz + i * 4) = z4v;
        return;
    }
    __shared__ __align__(16) unsigned short AN[64][128];
    const int tid = threadIdx.x;
    const int lane = tid & 63;
    const int wid = tid >> 6;
    const int lr = lane & 15;
    const int lg = lane >> 4;
    const int mycol = wid * 16 + lr;
    const float bm1_l = bm1v[mycol];
    const f32x4 z4 = {0.f, 0.f, 0.f, 0.f};
    const int n0 = blockIdx.x * 64;

    {
        const int i = tid >> 3, j = tid & 7;
        const int n = n0 + i;
        const bool ok = (n < NN);
        #pragma unroll
        for (int gi = 0; gi < 2; ++gi) {
            const int g = j + gi * 8;
            short8 v = {0,0,0,0,0,0,0,0};
            if (ok) {
                const float* xp = x + (size_t)n * HIDC + (g << 3);
                const f32x4 a = *reinterpret_cast<const f32x4*>(xp);
                const f32x4 b = *reinterpret_cast<const f32x4*>(xp + 4);
                #pragma unroll
                for (int cc = 0; cc < 4; ++cc) { v[cc] = (short)f2bf(a[cc]); v[cc+4] = (short)f2bf(b[cc]); }
            }
            *reinterpret_cast<short8*>(&AN[i][0] + ((g ^ (i & 7)) << 3)) = v;
        }
    }
    __syncthreads();

    f32x4 accp[4] = {z4, z4, z4, z4};
    f32x4 accq[4] = {z4, z4, z4, z4};
    #pragma unroll
    for (int kk = 0; kk < 4; ++kk) {
        const bf16x8 ba = *reinterpret_cast<const bf16x8*>(wta + mycol * 128 + kk * 32 + lg * 8);
        const bf16x8 bb = *reinterpret_cast<const bf16x8*>(wtb + mycol * 128 + kk * 32 + lg * 8);
        #pragma unroll
        for (int m = 0; m < 4; ++m) {
            const int r = m * 16 + lr;
            const bf16x8 a = *reinterpret_cast<const bf16x8*>(
                &AN[r][0] + (((kk * 4 + lg) ^ (r & 7)) << 3));
            accp[m] = __builtin_amdgcn_mfma_f32_16x16x32_bf16(a, ba, accp[m], 0, 0, 0);
            accq[m] = __builtin_amdgcn_mfma_f32_16x16x32_bf16(a, bb, accq[m], 0, 0, 0);
        }
    }
    #pragma unroll
    for (int m = 0; m < 4; ++m) {
        #pragma unroll
        for (int q = 0; q < 4; ++q) {
            const int n = n0 + m * 16 + lg * 4 + q;
            if (n < NN) {
                Pb[(size_t)n * HIDC + mycol] = f2bf(accp[m][q] + bm1_l);
                Qb[(size_t)n * HIDC + mycol] = f2bf(accq[m][q]);
            }
        }
    }
}

// ---------------- edge kernel: zero barriers in loop, wave-owned 16-edge tiles ----------------
// Transposed GEMMs: A = weights (LDS), B = per-edge features (regs).
// D layout: col = lane&15 = edge, row = (lane>>4)*4+q (+16*mt) = hid.
// Cross-tile P/Q register prefetch hides gather latency. exp+rcp silu (LUT regressed, r9).
__launch_bounds__(1024, 4)
__global__ void edge_kernel(
    const unsigned short* __restrict__ Pb, const unsigned short* __restrict__ Qb,
    const int4* __restrict__ epck,
    const unsigned short* __restrict__ wt2g, const unsigned short* __restrict__ wtc1g,
    const float* __restrict__ Wm1,
    const float* __restrict__ bm2v, const float* __restrict__ bc1v,
    const float* __restrict__ wc2v, const float* __restrict__ bc2v,
    float* __restrict__ agg, float* __restrict__ cagg)
{
    __shared__ __align__(16) unsigned short wt2L[128][128];   // 32 KB
    __shared__ __align__(16) unsigned short wtc1L[128][128];  // 32 KB
    __shared__ __align__(16) float cons[4][128];              // bm2, bc1, wc2, -
    __shared__ __align__(16) float w4F[128][4];               // W1 rows 256..259 (f32), 2 KB
    __shared__ __align__(16) unsigned int MW[16][16 * 68];    // per-wave scratch, 68 KB

    const int tid = threadIdx.x;
    const int lane = tid & 63;
    const int wid = tid >> 6;

    // one-time fills (only barrier in the kernel)
    #pragma unroll
    for (int i = tid; i < 2048; i += 1024) {
        const int n = i >> 4, G = i & 15;
        *reinterpret_cast<short8*>(&wt2L[n][(G ^ (n & 7)) << 3]) =
            *reinterpret_cast<const short8*>(wt2g + n * 128 + G * 8);
    }
    #pragma unroll
    for (int i = tid; i < 2048; i += 1024) {
        const int n = i >> 4, G = i & 15;
        *reinterpret_cast<short8*>(&wtc1L[n][(G ^ (n & 7)) << 3]) =
            *reinterpret_cast<const short8*>(wtc1g + n * 128 + G * 8);
    }
    if (tid < 512) { const int h = tid >> 2, w = tid & 3; w4F[h][w] = Wm1[(256 + w) * 128 + h]; }
    if (tid < 384) {
        const int r = tid >> 7, j = tid & 127;
        cons[r][j] = (r == 0) ? bm2v[j] : (r == 1) ? bc1v[j] : wc2v[j];
    }
    __syncthreads();
    const float bc2s = bc2v[0];

    const int c = lane & 15, g = lane >> 4, c7 = c & 7;
    unsigned int* mw = &MW[wid][0];
    const f32x4 z4 = {0.f, 0.f, 0.f, 0.f};

    // balanced tile split over 4096 waves: 40000 = 3136*10 + 960*9
    const int gw = blockIdx.x * 16 + wid;    // 0..4095
    int t = gw * 9 + (gw < 3136 ? gw : 3136);
    const int tEnd = t + 9 + (gw < 3136 ? 1 : 0);

    int cur = -1; float s0a = 0.f, s1a = 0.f;      // cross-tile agg run accumulators

    auto flushA = [&]() {
        const float u1 = __shfl(s0a, lane >> 1, 64);
        const float v1 = __shfl(s1a, lane >> 1, 64);
        atomicAdd(&agg[(size_t)cur * HIDC + lane], (lane & 1) ? v1 : u1);
        const float u2 = __shfl(s0a, 32 + (lane >> 1), 64);
        const float v2 = __shfl(s1a, 32 + (lane >> 1), 64);
        atomicAdd(&agg[(size_t)cur * HIDC + 64 + lane], (lane & 1) ? v2 : u2);
    };

    int4 eA = epck[(size_t)(t * 16 + c) * 2 + 0];
    int4 eB = epck[(size_t)(t * 16 + c) * 2 + 1];

    // prime first tile's P/Q gathers
    bf16x8 Pf[4], Qf[4];
    {
        const int s0 = eB.w & 0xffff;
        const int d0 = ((unsigned)eB.w) >> 16;
        #pragma unroll
        for (int kk = 0; kk < 4; ++kk) {
            Pf[kk] = *reinterpret_cast<const bf16x8*>(Pb + (size_t)s0 * HIDC + kk * 32 + g * 8);
            Qf[kk] = *reinterpret_cast<const bf16x8*>(Qb + (size_t)d0 * HIDC + kk * 32 + g * 8);
        }
    }

    for (; t < tEnd; ++t) {
        const float dx = __int_as_float(eA.x);
        const float dy = __int_as_float(eA.y);
        const float dz = __int_as_float(eA.z);
        const float dist = __int_as_float(eA.w);
        const float ea0 = __int_as_float(eB.x);
        const float ea1 = __int_as_float(eB.y);
        const float ea2 = __int_as_float(eB.z);
        const int s = eB.w & 0xffff;
        const bool more = (t + 1 < tEnd);

        if (more) {   // prefetch next tile's edge data
            eA = epck[(size_t)((t + 1) * 16 + c) * 2 + 0];
            eB = epck[(size_t)((t + 1) * 16 + c) * 2 + 1];
        }

        // build h (per kk) and run GEMM2 immediately (consumes Pf/Qf)
        f32x4 acc2[8] = {z4, z4, z4, z4, z4, z4, z4, z4};
        #pragma unroll
        for (int kk = 0; kk < 4; ++kk) {
            const int hb = kk * 32 + g * 8;
            uint4v hw;
            #pragma unroll
            for (int jp = 0; jp < 4; ++jp) {
                float hv[2];
                #pragma unroll
                for (int u = 0; u < 2; ++u) {
                    const int j = 2 * jp + u;
                    const f32x4 w = *reinterpret_cast<const f32x4*>(&w4F[hb + j][0]);
                    const float hvv = (float)Pf[kk][j] + (float)Qf[kk][j]
                        + dist * w[0] + ea0 * w[1] + ea1 * w[2] + ea2 * w[3];
                    hv[u] = silu_f(hvv);
                }
                hw[jp] = cvtpk(hv[0], hv[1]);
            }
            const bf16x8 hf = *reinterpret_cast<const bf16x8*>(&hw);
            __builtin_amdgcn_s_setprio(1);
            #pragma unroll
            for (int mt = 0; mt < 8; ++mt) {
                const bf16x8 a = *reinterpret_cast<const bf16x8*>(
                    &wt2L[mt * 16 + c][(((kk << 2) + g) ^ c7) << 3]);
                acc2[mt] = __builtin_amdgcn_mfma_f32_16x16x32_bf16(a, hf, acc2[mt], 0, 0, 0);
            }
            __builtin_amdgcn_s_setprio(0);
        }

        // Pf/Qf now dead: issue NEXT tile's P/Q gathers (latency hides under the rest)
        if (more) {
            const int sN = eB.w & 0xffff;
            const int dN = ((unsigned)eB.w) >> 16;
            #pragma unroll
            for (int kk = 0; kk < 4; ++kk) {
                Pf[kk] = *reinterpret_cast<const bf16x8*>(Pb + (size_t)sN * HIDC + kk * 32 + g * 8);
                Qf[kk] = *reinterpret_cast<const bf16x8*>(Qb + (size_t)dN * HIDC + kk * 32 + g * 8);
            }
        }

        // epilogue: silu+bm2, pack msg pairs, write wave scratch
        #pragma unroll
        for (int mt = 0; mt < 8; ++mt) {
            const f32x4 bm2q = *reinterpret_cast<const f32x4*>(&cons[0][mt * 16 + 4 * g]);
            const unsigned int p0 = cvtpk(silu_f(acc2[mt][0] + bm2q[0]), silu_f(acc2[mt][1] + bm2q[1]));
            const unsigned int p1 = cvtpk(silu_f(acc2[mt][2] + bm2q[2]), silu_f(acc2[mt][3] + bm2q[3]));
            *reinterpret_cast<uint2v*>(&mw[c * 68 + 8 * mt + 2 * g]) = (uint2v){p0, p1};
        }
        asm volatile("s_waitcnt lgkmcnt(0)" ::: "memory");
        __builtin_amdgcn_sched_barrier(0);

        // GEMM3: t^T = Wc1 * msg^T
        f32x4 acc3[8] = {z4, z4, z4, z4, z4, z4, z4, z4};
        #pragma unroll
        for (int kk = 0; kk < 4; ++kk) {
            const bf16x8 bfr = *reinterpret_cast<const bf16x8*>(&mw[c * 68 + 16 * kk + 4 * g]);
            __builtin_amdgcn_s_setprio(1);
            #pragma unroll
            for (int mt = 0; mt < 8; ++mt) {
                const bf16x8 a = *reinterpret_cast<const bf16x8*>(
                    &wtc1L[mt * 16 + c][(((kk << 2) + g) ^ c7) << 3]);
                acc3[mt] = __builtin_amdgcn_mfma_f32_16x16x32_bf16(a, bfr, acc3[mt], 0, 0, 0);
            }
            __builtin_amdgcn_s_setprio(0);
        }

        // coord weight: cw = Wc2 . silu(t) + bc2, reduce over g-groups
        float cw = 0.f;
        #pragma unroll
        for (int mt = 0; mt < 8; ++mt) {
            const f32x4 bc1q = *reinterpret_cast<const f32x4*>(&cons[1][mt * 16 + 4 * g]);
            const f32x4 wc2q = *reinterpret_cast<const f32x4*>(&cons[2][mt * 16 + 4 * g]);
            #pragma unroll
            for (int q = 0; q < 4; ++q)
                cw += silu_f(acc3[mt][q] + bc1q[q]) * wc2q[q];
        }
        cw += __shfl_xor(cw, 16, 64);
        cw += __shfl_xor(cw, 32, 64);
        cw += bc2s;

        // coord: segmented inclusive scan over c (runs contiguous by src)
        float vx = dx * cw, vy = dy * cw, vz = dz * cw;
        #pragma unroll
        for (int dd = 1; dd < 16; dd <<= 1) {
            const int su = __shfl_up(s, dd, 16);
            const float ux = __shfl_up(vx, dd, 16);
            const float uy = __shfl_up(vy, dd, 16);
            const float uz = __shfl_up(vz, dd, 16);
            if (c >= dd && su == s) { vx += ux; vy += uy; vz += uz; }
        }
        {
            const int sdn = __shfl_down(s, 1, 16);
            if (g == 0 && (c == 15 || sdn != s)) {
                atomicAdd(&cagg[s * 3 + 0], vx);
                atomicAdd(&cagg[s * 3 + 1], vy);
                atomicAdd(&cagg[s * 3 + 2], vz);
            }
        }

        // serial segmented column-sum over the 16 edges (runs carried across tiles),
        // LDS reads batched in chunks of 8 to amortize latency
        #pragma unroll
        for (int eh = 0; eh < 2; ++eh) {
            unsigned int rv8[8];
            #pragma unroll
            for (int e = 0; e < 8; ++e) rv8[e] = mw[(eh * 8 + e) * 68 + lane];
            #pragma unroll
            for (int e = 0; e < 8; ++e) {
                const int se = __builtin_amdgcn_readlane(s, eh * 8 + e);
                const float f0 = __uint_as_float(rv8[e] << 16);
                const float f1 = __uint_as_float(rv8[e] & 0xffff0000u);
                if (se != cur) {
                    if (cur >= 0) flushA();
                    cur = se; s0a = f0; s1a = f1;
                } else { s0a += f0; s1a += f1; }
            }
        }
    }
    if (cur >= 0) flushA();
}

// ---------------- node kernel: node MLP + pos_new ----------------
__launch_bounds__(512, 4)
__global__ void node_kernel(
    const float* __restrict__ x, const float* __restrict__ agg,
    const float* __restrict__ cagg,
    const unsigned short* __restrict__ wtn1, const unsigned short* __restrict__ wtn2,
    const float* __restrict__ bn1v, const float* __restrict__ bn2v,
    const float* __restrict__ pos,
    float* __restrict__ outx, float* __restrict__ outp)
{
    __shared__ __align__(16) unsigned short AN[64][256];
    __shared__ __align__(16) unsigned short HN[64][HIDC];
    const int tid = threadIdx.x;
    const int lane = tid & 63;
    const int wid = tid >> 6;
    const int lr = lane & 15;
    const int lg = lane >> 4;
    const int mycol = wid * 16 + lr;
    const float bn1_l = bn1v[mycol];
    const float bn2_l = bn2v[mycol];
    const f32x4 z4 = {0.f, 0.f, 0.f, 0.f};
    const int n0 = blockIdx.x * 64;

    {
        const int i = tid >> 3, j = tid & 7;
        const int n = n0 + i;
        const bool ok = (n < NN);
        #pragma unroll
        for (int gi = 0; gi < 4; ++gi) {
            const int g = j + gi * 8;                      // 0..31
            short8 v = {0,0,0,0,0,0,0,0};
            if (ok) {
                const float* sp = (g < 16) ? (x + (size_t)n * HIDC + (g << 3))
                                           : (agg + (size_t)n * HIDC + ((g - 16) << 3));
                const f32x4 a = *reinterpret_cast<const f32x4*>(sp);
                const f32x4 b = *reinterpret_cast<const f32x4*>(sp + 4);
                #pragma unroll
                for (int cc = 0; cc < 4; ++cc) { v[cc] = (short)f2bf(a[cc]); v[cc+4] = (short)f2bf(b[cc]); }
            }
            *reinterpret_cast<short8*>(&AN[i][0] + ((g ^ (i & 7)) << 3)) = v;
        }
    }
    __syncthreads();

    f32x4 acc[4] = {z4, z4, z4, z4};
    #pragma unroll
    for (int kk = 0; kk < 8; ++kk) {
        const bf16x8 b = *reinterpret_cast<const bf16x8*>(wtn1 + mycol * 256 + kk * 32 + lg * 8);
        #pragma unroll
        for (int m = 0; m < 4; ++m) {
            const int r = m * 16 + lr;
            const bf16x8 a = *reinterpret_cast<const bf16x8*>(
                &AN[r][0] + (((kk * 4 + lg) ^ (r & 7)) << 3));
            acc[m] = __builtin_amdgcn_mfma_f32_16x16x32_bf16(a, b, acc[m], 0, 0, 0);
        }
    }
    #pragma unroll
    for (int m = 0; m < 4; ++m) {
        #pragma unroll
        for (int q = 0; q < 4; ++q) {
            const int r = m * 16 + lg * 4 + q;
            HN[r][mycol ^ ((r & 7) << 3)] = f2bf(silu_f(acc[m][q] + bn1_l));
        }
    }
    __syncthreads();

    f32x4 acc2[4] = {z4, z4, z4, z4};
    #pragma unroll
    for (int kk = 0; kk < 4; ++kk) {
        const bf16x8 b = *reinterpret_cast<const bf16x8*>(wtn2 + mycol * 128 + kk * 32 + lg * 8);
        #pragma unroll
        for (int m = 0; m < 4; ++m) {
            const int r = m * 16 + lr;
            const bf16x8 a = *reinterpret_cast<const bf16x8*>(
                &HN[r][0] + (((kk * 4 + lg) ^ (r & 7)) << 3));
            acc2[m] = __builtin_amdgcn_mfma_f32_16x16x32_bf16(a, b, acc2[m], 0, 0, 0);
        }
    }
    #pragma unroll
    for (int m = 0; m < 4; ++m) {
        #pragma unroll
        for (int q = 0; q < 4; ++q) {
            const int n = n0 + m * 16 + lg * 4 + q;
            if (n < NN) outx[(size_t)n * HIDC + mycol] = acc2[m][q] + bn2_l;
        }
    }
    if (tid < 192) {
        const int r = n0 + tid / 3;
        const int d2 = tid - (tid / 3) * 3;
        if (r < NN) outp[r * 3 + d2] = pos[r * 3 + d2] + cagg[r * 3 + d2];
    }
}

// ---------------- launch ----------------
extern "C" void kernel_launch(void* const* d_in, const int* in_sizes, int n_in,
                              void* d_out, int out_size, void* d_ws, size_t ws_size,
                              hipStream_t stream)
{
    const float* x   = (const float*)d_in[0];
    const float* pos = (const float*)d_in[1];
    const int*   ei  = (const int*)d_in[2];
    const float* ea  = (const float*)d_in[3];
    const float* Wm1 = (const float*)d_in[4];
    const float* bm1 = (const float*)d_in[5];
    const float* Wm2 = (const float*)d_in[6];
    const float* bm2 = (const float*)d_in[7];
    const float* Wn1 = (const float*)d_in[8];
    const float* bn1 = (const float*)d_in[9];
    const float* Wn2 = (const float*)d_in[10];
    const float* bn2 = (const float*)d_in[11];
    const float* Wc1 = (const float*)d_in[12];
    const float* bc1 = (const float*)d_in[13];
    const float* Wc2 = (const float*)d_in[14];
    const float* bc2 = (const float*)d_in[15];

    char* ws = (char*)d_ws;
    unsigned short* Pb   = (unsigned short*)(ws);              // 12,800,000
    unsigned short* Qb   = (unsigned short*)(ws + 12800000);   // 12,800,000
    float* agg           = (float*)(ws + 25600000);            // 25,600,000
    float* cagg          = (float*)(ws + 51200000);            //    600,000 (contiguous after agg)
    int*   cnt           = (int*)(ws + 51800000);              //    200,000
    int*   offs2         = (int*)(ws + 52000000);              //    200,000
    int4*  epck          = (int4*)(ws + 52201024);             // 20,480,000
    unsigned short* wta  = (unsigned short*)(ws + 72681024);   //     32,768
    unsigned short* wtb  = (unsigned short*)(ws + 72713792);   //     32,768
    unsigned short* wt2  = (unsigned short*)(ws + 72746560);   //     32,768
    unsigned short* wtc1 = (unsigned short*)(ws + 72779328);   //     32,768
    unsigned short* wtn1 = (unsigned short*)(ws + 72812096);   //     65,536
    unsigned short* wtn2 = (unsigned short*)(ws + 72877632);   //     32,768

    float* outx = (float*)d_out;
    float* outp = outx + (size_t)NN * HIDC;

    hipMemsetAsync(cnt, 0, NN * sizeof(int), stream);
    convw_count_kernel<<<448 + 2500, 256, 0, stream>>>(Wm1, Wm2, Wc1, Wn1, Wn2, ei,
                                                       wta, wtb, wt2, wtc1, wtn1, wtn2, cnt);
    scan_fused_kernel<<<1, 1024, 0, stream>>>(cnt, offs2);
    scatter_kernel<<<2500, 256, 0, stream>>>(ei, pos, ea, offs2, epck);
    pq_kernel<<<NTILES + 200, 512, 0, stream>>>(x, wta, wtb, bm1, Pb, Qb, agg);
    edge_kernel<<<256, 1024, 0, stream>>>(Pb, Qb, epck, wt2, wtc1, Wm1,
                                          bm2, bc1, Wc2, bc2, agg, cagg);
    node_kernel<<<NTILES, 512, 0, stream>>>(x, agg, cagg, wtn1, wtn2, bn1, bn2,
                                            pos, outx, outp);
}

// Round 11
// 244.932 us; speedup vs baseline: 1.3191x; 1.3191x over previous
//
#include <hip/hip_runtime.h>
#include <math.h>

#define NN 50000
#define NE 640000
#define HIDC 128
#define NTILES ((NN + 63)/64)

typedef short  short8 __attribute__((ext_vector_type(8)));
typedef __bf16 bf16x8 __attribute__((ext_vector_type(8)));
typedef float  f32x4  __attribute__((ext_vector_type(4)));
typedef unsigned int uint2v __attribute__((ext_vector_type(2)));
typedef unsigned int uint4v __attribute__((ext_vector_type(4)));

__device__ __forceinline__ unsigned short f2bf(float f) {
    unsigned int b = __float_as_uint(f);
    b += 0x7FFFu + ((b >> 16) & 1u);          // RTNE
    return (unsigned short)(b >> 16);
}
// silu via v_rcp (1 op) instead of IEEE div (~10 ops). ~1ulp, invisible at bf16.
__device__ __forceinline__ float silu_f(float v) {
    return v * __builtin_amdgcn_rcpf(1.0f + __expf(-v));
}
// packed RTNE f32->bf16 pair (1 VALU op)
__device__ __forceinline__ unsigned int cvtpk(float a, float b) {
    unsigned int r;
    asm("v_cvt_pk_bf16_f32 %0, %1, %2" : "=v"(r) : "v"(a), "v"(b));
    return r;
}

// ---------------- merged prep: weight transposes + degree count ----------------
__global__ void convw_count_kernel(const float* __restrict__ Wm1, const float* __restrict__ Wm2,
                                   const float* __restrict__ Wc1, const float* __restrict__ Wn1,
                                   const float* __restrict__ Wn2, const int* __restrict__ ei,
                                   unsigned short* __restrict__ wta, unsigned short* __restrict__ wtb,
                                   unsigned short* __restrict__ wt2, unsigned short* __restrict__ wtc1,
                                   unsigned short* __restrict__ wtn1, unsigned short* __restrict__ wtn2,
                                   int* __restrict__ cnt) {
    if (blockIdx.x >= 448) {   // count part
        const int e = (blockIdx.x - 448) * 256 + threadIdx.x;
        if (e < NE) atomicAdd(&cnt[ei[e]], 1);
        return;
    }
    const int i = blockIdx.x * 256 + threadIdx.x;
    if (i < 16384) {
        const int n = i >> 7, k = i & 127;
        wta[i] = f2bf(Wm1[k * 128 + n]);
    } else if (i < 32768) {
        const int j = i - 16384; const int n = j >> 7, k = j & 127;
        wtb[j] = f2bf(Wm1[(128 + k) * 128 + n]);
    } else if (i < 49152) {
        const int j = i - 32768; const int n = j >> 7, k = j & 127;
        wt2[j] = f2bf(Wm2[k * 128 + n]);
    } else if (i < 65536) {
        const int j = i - 49152; const int n = j >> 7, k = j & 127;
        wtc1[j] = f2bf(Wc1[k * 128 + n]);
    } else if (i < 98304) {
        const int j = i - 65536; const int n = j >> 8, k = j & 255;
        wtn1[j] = f2bf(Wn1[k * 128 + n]);
    } else if (i < 114688) {
        const int j = i - 98304; const int n = j >> 7, k = j & 127;
        wtn2[j] = f2bf(Wn2[k * 128 + n]);
    }
}

// ---------------- CSR scan (parallel 3-kernel chain; single-block fused version
// regressed ~75us in round 10 — one CU doing serial latency-bound work) ----------------
__global__ void scanA_kernel(const int* __restrict__ cnt, int* __restrict__ part) {
    __shared__ int ws[4];
    const int t = threadIdx.x, b = blockIdx.x;
    int v = (t < 200) ? cnt[b * 200 + t] : 0;
    #pragma unroll
    for (int d2 = 1; d2 < 64; d2 <<= 1) v += __shfl_xor(v, d2, 64);
    if ((t & 63) == 0) ws[t >> 6] = v;
    __syncthreads();
    if (t == 0) part[b] = ws[0] + ws[1] + ws[2] + ws[3];
}

__global__ void scanB_kernel(int* __restrict__ part) {   // 1 block, 64 threads
    const int t = threadIdx.x;
    int v[4]; int tot = 0;
    #pragma unroll
    for (int i = 0; i < 4; ++i) {
        const int idx = t * 4 + i;
        v[i] = (idx < 250) ? part[idx] : 0;
        tot += v[i];
    }
    int incl = tot;
    #pragma unroll
    for (int d2 = 1; d2 < 64; d2 <<= 1) { int u = __shfl_up(incl, d2, 64); if (t >= d2) incl += u; }
    int ex = incl - tot;
    #pragma unroll
    for (int i = 0; i < 4; ++i) {
        const int idx = t * 4 + i;
        if (idx < 250) part[idx] = ex;
        ex += v[i];
    }
}

__global__ void scanC_kernel(const int* __restrict__ cnt, const int* __restrict__ part,
                             int* __restrict__ offs2) {
    __shared__ int wex[4];
    const int t = threadIdx.x, b = blockIdx.x;
    const int lane = t & 63, w = t >> 6;
    int v = (t < 200) ? cnt[b * 200 + t] : 0;
    int incl = v;
    #pragma unroll
    for (int d2 = 1; d2 < 64; d2 <<= 1) { int u = __shfl_up(incl, d2, 64); if (lane >= d2) incl += u; }
    if (lane == 63) wex[w] = incl;
    __syncthreads();
    if (t == 0) { int a = 0; for (int i = 0; i < 4; ++i) { int x = wex[i]; wex[i] = a; a += x; } }
    __syncthreads();
    if (t < 200) offs2[b * 200 + t] = incl - v + wex[w] + part[b];
}

// scatter + edge-data pack: epck[slot] = {dx,dy,dz,dist | ea0,ea1,ea2, src|dst<<16}
__global__ void scatter_kernel(const int* __restrict__ ei, const float* __restrict__ pos,
                               const float* __restrict__ eattr,
                               int* __restrict__ offs2, int4* __restrict__ epck) {
    const int e = blockIdx.x * 256 + threadIdx.x;
    if (e >= NE) return;
    const int s = ei[e], d = ei[NE + e];
    const int slot = atomicAdd(&offs2[s], 1);
    const float dx = pos[s*3+0] - pos[d*3+0];
    const float dy = pos[s*3+1] - pos[d*3+1];
    const float dz = pos[s*3+2] - pos[d*3+2];
    const float dist = sqrtf(dx*dx + dy*dy + dz*dz);
    int4 a, b;
    a.x = __float_as_int(dx); a.y = __float_as_int(dy);
    a.z = __float_as_int(dz); a.w = __float_as_int(dist);
    b.x = __float_as_int(eattr[e*3+0]); b.y = __float_as_int(eattr[e*3+1]);
    b.z = __float_as_int(eattr[e*3+2]); b.w = s | (d << 16);
    epck[(size_t)slot * 2 + 0] = a;
    epck[(size_t)slot * 2 + 1] = b;
}

// ---------------- P/Q precompute + agg/cagg zeroing (fused grid) ----------------
__launch_bounds__(512, 4)
__global__ void pq_kernel(const float* __restrict__ x,
                          const unsigned short* __restrict__ wta,
                          const unsigned short* __restrict__ wtb,
                          const float* __restrict__ bm1v,
                          unsigned short* __restrict__ Pb, unsigned short* __restrict__ Qb,
                          float* __restrict__ aggz)
{
    if (blockIdx.x >= NTILES) {   // zero section: agg (6.4M f32) + cagg (150k f32) contiguous
        const int zt = (blockIdx.x - NTILES) * 512 + threadIdx.x;   // 0..102399
        const f32x4 z4v = {0.f, 0.f, 0.f, 0.f};
        for (size_t i = zt; i < 1637500; i += 102400)
            *reinterpret_cast<f32x4*>(aggz + i * 4) = z4v;
        return;
    }
    __shared__ __align__(16) unsigned short AN[64][128];
    const int tid = threadIdx.x;
    const int lane = tid & 63;
    const int wid = tid >> 6;
    const int lr = lane & 15;
    const int lg = lane >> 4;
    const int mycol = wid * 16 + lr;
    const float bm1_l = bm1v[mycol];
    const f32x4 z4 = {0.f, 0.f, 0.f, 0.f};
    const int n0 = blockIdx.x * 64;

    {
        const int i = tid >> 3, j = tid & 7;
        const int n = n0 + i;
        const bool ok = (n < NN);
        #pragma unroll
        for (int gi = 0; gi < 2; ++gi) {
            const int g = j + gi * 8;
            short8 v = {0,0,0,0,0,0,0,0};
            if (ok) {
                const float* xp = x + (size_t)n * HIDC + (g << 3);
                const f32x4 a = *reinterpret_cast<const f32x4*>(xp);
                const f32x4 b = *reinterpret_cast<const f32x4*>(xp + 4);
                #pragma unroll
                for (int cc = 0; cc < 4; ++cc) { v[cc] = (short)f2bf(a[cc]); v[cc+4] = (short)f2bf(b[cc]); }
            }
            *reinterpret_cast<short8*>(&AN[i][0] + ((g ^ (i & 7)) << 3)) = v;
        }
    }
    __syncthreads();

    f32x4 accp[4] = {z4, z4, z4, z4};
    f32x4 accq[4] = {z4, z4, z4, z4};
    #pragma unroll
    for (int kk = 0; kk < 4; ++kk) {
        const bf16x8 ba = *reinterpret_cast<const bf16x8*>(wta + mycol * 128 + kk * 32 + lg * 8);
        const bf16x8 bb = *reinterpret_cast<const bf16x8*>(wtb + mycol * 128 + kk * 32 + lg * 8);
        #pragma unroll
        for (int m = 0; m < 4; ++m) {
            const int r = m * 16 + lr;
            const bf16x8 a = *reinterpret_cast<const bf16x8*>(
                &AN[r][0] + (((kk * 4 + lg) ^ (r & 7)) << 3));
            accp[m] = __builtin_amdgcn_mfma_f32_16x16x32_bf16(a, ba, accp[m], 0, 0, 0);
            accq[m] = __builtin_amdgcn_mfma_f32_16x16x32_bf16(a, bb, accq[m], 0, 0, 0);
        }
    }
    #pragma unroll
    for (int m = 0; m < 4; ++m) {
        #pragma unroll
        for (int q = 0; q < 4; ++q) {
            const int n = n0 + m * 16 + lg * 4 + q;
            if (n < NN) {
                Pb[(size_t)n * HIDC + mycol] = f2bf(accp[m][q] + bm1_l);
                Qb[(size_t)n * HIDC + mycol] = f2bf(accq[m][q]);
            }
        }
    }
}

// ---------------- edge kernel: zero barriers in loop, wave-owned 16-edge tiles ----------------
// Transposed GEMMs: A = weights (LDS), B = per-edge features (regs).
// D layout: col = lane&15 = edge, row = (lane>>4)*4+q (+16*mt) = hid.
// Cross-tile P/Q register prefetch; exp+rcp silu; compiler-managed LDS waits.
__launch_bounds__(1024, 4)
__global__ void edge_kernel(
    const unsigned short* __restrict__ Pb, const unsigned short* __restrict__ Qb,
    const int4* __restrict__ epck,
    const unsigned short* __restrict__ wt2g, const unsigned short* __restrict__ wtc1g,
    const float* __restrict__ Wm1,
    const float* __restrict__ bm2v, const float* __restrict__ bc1v,
    const float* __restrict__ wc2v, const float* __restrict__ bc2v,
    float* __restrict__ agg, float* __restrict__ cagg)
{
    __shared__ __align__(16) unsigned short wt2L[128][128];   // 32 KB
    __shared__ __align__(16) unsigned short wtc1L[128][128];  // 32 KB
    __shared__ __align__(16) float cons[4][128];              // bm2, bc1, wc2, -
    __shared__ __align__(16) float w4F[128][4];               // W1 rows 256..259 (f32), 2 KB
    __shared__ __align__(16) unsigned int MW[16][16 * 68];    // per-wave scratch, 68 KB

    const int tid = threadIdx.x;
    const int lane = tid & 63;
    const int wid = tid >> 6;

    // one-time fills (only barrier in the kernel)
    #pragma unroll
    for (int i = tid; i < 2048; i += 1024) {
        const int n = i >> 4, G = i & 15;
        *reinterpret_cast<short8*>(&wt2L[n][(G ^ (n & 7)) << 3]) =
            *reinterpret_cast<const short8*>(wt2g + n * 128 + G * 8);
    }
    #pragma unroll
    for (int i = tid; i < 2048; i += 1024) {
        const int n = i >> 4, G = i & 15;
        *reinterpret_cast<short8*>(&wtc1L[n][(G ^ (n & 7)) << 3]) =
            *reinterpret_cast<const short8*>(wtc1g + n * 128 + G * 8);
    }
    if (tid < 512) { const int h = tid >> 2, w = tid & 3; w4F[h][w] = Wm1[(256 + w) * 128 + h]; }
    if (tid < 384) {
        const int r = tid >> 7, j = tid & 127;
        cons[r][j] = (r == 0) ? bm2v[j] : (r == 1) ? bc1v[j] : wc2v[j];
    }
    __syncthreads();
    const float bc2s = bc2v[0];

    const int c = lane & 15, g = lane >> 4, c7 = c & 7;
    unsigned int* mw = &MW[wid][0];
    const f32x4 z4 = {0.f, 0.f, 0.f, 0.f};

    // balanced tile split over 4096 waves: 40000 = 3136*10 + 960*9
    const int gw = blockIdx.x * 16 + wid;    // 0..4095
    int t = gw * 9 + (gw < 3136 ? gw : 3136);
    const int tEnd = t + 9 + (gw < 3136 ? 1 : 0);

    int cur = -1; float s0a = 0.f, s1a = 0.f;      // cross-tile agg run accumulators

    auto flushA = [&]() {
        const float u1 = __shfl(s0a, lane >> 1, 64);
        const float v1 = __shfl(s1a, lane >> 1, 64);
        atomicAdd(&agg[(size_t)cur * HIDC + lane], (lane & 1) ? v1 : u1);
        const float u2 = __shfl(s0a, 32 + (lane >> 1), 64);
        const float v2 = __shfl(s1a, 32 + (lane >> 1), 64);
        atomicAdd(&agg[(size_t)cur * HIDC + 64 + lane], (lane & 1) ? v2 : u2);
    };

    int4 eA = epck[(size_t)(t * 16 + c) * 2 + 0];
    int4 eB = epck[(size_t)(t * 16 + c) * 2 + 1];

    // prime first tile's P/Q gathers
    bf16x8 Pf[4], Qf[4];
    {
        const int s0 = eB.w & 0xffff;
        const int d0 = ((unsigned)eB.w) >> 16;
        #pragma unroll
        for (int kk = 0; kk < 4; ++kk) {
            Pf[kk] = *reinterpret_cast<const bf16x8*>(Pb + (size_t)s0 * HIDC + kk * 32 + g * 8);
            Qf[kk] = *reinterpret_cast<const bf16x8*>(Qb + (size_t)d0 * HIDC + kk * 32 + g * 8);
        }
    }

    for (; t < tEnd; ++t) {
        const float dx = __int_as_float(eA.x);
        const float dy = __int_as_float(eA.y);
        const float dz = __int_as_float(eA.z);
        const float dist = __int_as_float(eA.w);
        const float ea0 = __int_as_float(eB.x);
        const float ea1 = __int_as_float(eB.y);
        const float ea2 = __int_as_float(eB.z);
        const int s = eB.w & 0xffff;
        const bool more = (t + 1 < tEnd);

        if (more) {   // prefetch next tile's edge data
            eA = epck[(size_t)((t + 1) * 16 + c) * 2 + 0];
            eB = epck[(size_t)((t + 1) * 16 + c) * 2 + 1];
        }

        // build h (per kk) and run GEMM2 immediately (consumes Pf/Qf)
        f32x4 acc2[8] = {z4, z4, z4, z4, z4, z4, z4, z4};
        #pragma unroll
        for (int kk = 0; kk < 4; ++kk) {
            const int hb = kk * 32 + g * 8;
            uint4v hw;
            #pragma unroll
            for (int jp = 0; jp < 4; ++jp) {
                float hv[2];
                #pragma unroll
                for (int u = 0; u < 2; ++u) {
                    const int j = 2 * jp + u;
                    const f32x4 w = *reinterpret_cast<const f32x4*>(&w4F[hb + j][0]);
                    const float hvv = (float)Pf[kk][j] + (float)Qf[kk][j]
                        + dist * w[0] + ea0 * w[1] + ea1 * w[2] + ea2 * w[3];
                    hv[u] = silu_f(hvv);
                }
                hw[jp] = cvtpk(hv[0], hv[1]);
            }
            const bf16x8 hf = *reinterpret_cast<const bf16x8*>(&hw);
            __builtin_amdgcn_s_setprio(1);
            #pragma unroll
            for (int mt = 0; mt < 8; ++mt) {
                const bf16x8 a = *reinterpret_cast<const bf16x8*>(
                    &wt2L[mt * 16 + c][(((kk << 2) + g) ^ c7) << 3]);
                acc2[mt] = __builtin_amdgcn_mfma_f32_16x16x32_bf16(a, hf, acc2[mt], 0, 0, 0);
            }
            __builtin_amdgcn_s_setprio(0);
        }

        // Pf/Qf now dead: issue NEXT tile's P/Q gathers (latency hides under the rest)
        if (more) {
            const int sN = eB.w & 0xffff;
            const int dN = ((unsigned)eB.w) >> 16;
            #pragma unroll
            for (int kk = 0; kk < 4; ++kk) {
                Pf[kk] = *reinterpret_cast<const bf16x8*>(Pb + (size_t)sN * HIDC + kk * 32 + g * 8);
                Qf[kk] = *reinterpret_cast<const bf16x8*>(Qb + (size_t)dN * HIDC + kk * 32 + g * 8);
            }
        }

        // epilogue: silu+bm2, pack msg pairs, write wave scratch
        #pragma unroll
        for (int mt = 0; mt < 8; ++mt) {
            const f32x4 bm2q = *reinterpret_cast<const f32x4*>(&cons[0][mt * 16 + 4 * g]);
            const unsigned int p0 = cvtpk(silu_f(acc2[mt][0] + bm2q[0]), silu_f(acc2[mt][1] + bm2q[1]));
            const unsigned int p1 = cvtpk(silu_f(acc2[mt][2] + bm2q[2]), silu_f(acc2[mt][3] + bm2q[3]));
            *reinterpret_cast<uint2v*>(&mw[c * 68 + 8 * mt + 2 * g]) = (uint2v){p0, p1};
        }
        // (compiler inserts the lgkmcnt for the same-wave MW write->read dependency)

        // GEMM3: t^T = Wc1 * msg^T
        f32x4 acc3[8] = {z4, z4, z4, z4, z4, z4, z4, z4};
        #pragma unroll
        for (int kk = 0; kk < 4; ++kk) {
            const bf16x8 bfr = *reinterpret_cast<const bf16x8*>(&mw[c * 68 + 16 * kk + 4 * g]);
            __builtin_amdgcn_s_setprio(1);
            #pragma unroll
            for (int mt = 0; mt < 8; ++mt) {
                const bf16x8 a = *reinterpret_cast<const bf16x8*>(
                    &wtc1L[mt * 16 + c][(((kk << 2) + g) ^ c7) << 3]);
                acc3[mt] = __builtin_amdgcn_mfma_f32_16x16x32_bf16(a, bfr, acc3[mt], 0, 0, 0);
            }
            __builtin_amdgcn_s_setprio(0);
        }

        // coord weight: cw = Wc2 . silu(t) + bc2, reduce over g-groups
        float cw = 0.f;
        #pragma unroll
        for (int mt = 0; mt < 8; ++mt) {
            const f32x4 bc1q = *reinterpret_cast<const f32x4*>(&cons[1][mt * 16 + 4 * g]);
            const f32x4 wc2q = *reinterpret_cast<const f32x4*>(&cons[2][mt * 16 + 4 * g]);
            #pragma unroll
            for (int q = 0; q < 4; ++q)
                cw += silu_f(acc3[mt][q] + bc1q[q]) * wc2q[q];
        }
        cw += __shfl_xor(cw, 16, 64);
        cw += __shfl_xor(cw, 32, 64);
        cw += bc2s;

        // coord: segmented inclusive scan over c (runs contiguous by src)
        float vx = dx * cw, vy = dy * cw, vz = dz * cw;
        #pragma unroll
        for (int dd = 1; dd < 16; dd <<= 1) {
            const int su = __shfl_up(s, dd, 16);
            const float ux = __shfl_up(vx, dd, 16);
            const float uy = __shfl_up(vy, dd, 16);
            const float uz = __shfl_up(vz, dd, 16);
            if (c >= dd && su == s) { vx += ux; vy += uy; vz += uz; }
        }
        {
            const int sdn = __shfl_down(s, 1, 16);
            if (g == 0 && (c == 15 || sdn != s)) {
                atomicAdd(&cagg[s * 3 + 0], vx);
                atomicAdd(&cagg[s * 3 + 1], vy);
                atomicAdd(&cagg[s * 3 + 2], vz);
            }
        }

        // serial segmented column-sum over the 16 edges (runs carried across tiles),
        // LDS reads batched in chunks of 8 to amortize latency
        #pragma unroll
        for (int eh = 0; eh < 2; ++eh) {
            unsigned int rv8[8];
            #pragma unroll
            for (int e = 0; e < 8; ++e) rv8[e] = mw[(eh * 8 + e) * 68 + lane];
            #pragma unroll
            for (int e = 0; e < 8; ++e) {
                const int se = __builtin_amdgcn_readlane(s, eh * 8 + e);
                const float f0 = __uint_as_float(rv8[e] << 16);
                const float f1 = __uint_as_float(rv8[e] & 0xffff0000u);
                if (se != cur) {
                    if (cur >= 0) flushA();
                    cur = se; s0a = f0; s1a = f1;
                } else { s0a += f0; s1a += f1; }
            }
        }
    }
    if (cur >= 0) flushA();
}

// ---------------- node kernel: node MLP + pos_new ----------------
__launch_bounds__(512, 4)
__global__ void node_kernel(
    const float* __restrict__ x, const float* __restrict__ agg,
    const float* __restrict__ cagg,
    const unsigned short* __restrict__ wtn1, const unsigned short* __restrict__ wtn2,
    const float* __restrict__ bn1v, const float* __restrict__ bn2v,
    const float* __restrict__ pos,
    float* __restrict__ outx, float* __restrict__ outp)
{
    __shared__ __align__(16) unsigned short AN[64][256];
    __shared__ __align__(16) unsigned short HN[64][HIDC];
    const int tid = threadIdx.x;
    const int lane = tid & 63;
    const int wid = tid >> 6;
    const int lr = lane & 15;
    const int lg = lane >> 4;
    const int mycol = wid * 16 + lr;
    const float bn1_l = bn1v[mycol];
    const float bn2_l = bn2v[mycol];
    const f32x4 z4 = {0.f, 0.f, 0.f, 0.f};
    const int n0 = blockIdx.x * 64;

    {
        const int i = tid >> 3, j = tid & 7;
        const int n = n0 + i;
        const bool ok = (n < NN);
        #pragma unroll
        for (int gi = 0; gi < 4; ++gi) {
            const int g = j + gi * 8;                      // 0..31
            short8 v = {0,0,0,0,0,0,0,0};
            if (ok) {
                const float* sp = (g < 16) ? (x + (size_t)n * HIDC + (g << 3))
                                           : (agg + (size_t)n * HIDC + ((g - 16) << 3));
                const f32x4 a = *reinterpret_cast<const f32x4*>(sp);
                const f32x4 b = *reinterpret_cast<const f32x4*>(sp + 4);
                #pragma unroll
                for (int cc = 0; cc < 4; ++cc) { v[cc] = (short)f2bf(a[cc]); v[cc+4] = (short)f2bf(b[cc]); }
            }
            *reinterpret_cast<short8*>(&AN[i][0] + ((g ^ (i & 7)) << 3)) = v;
        }
    }
    __syncthreads();

    f32x4 acc[4] = {z4, z4, z4, z4};
    #pragma unroll
    for (int kk = 0; kk < 8; ++kk) {
        const bf16x8 b = *reinterpret_cast<const bf16x8*>(wtn1 + mycol * 256 + kk * 32 + lg * 8);
        #pragma unroll
        for (int m = 0; m < 4; ++m) {
            const int r = m * 16 + lr;
            const bf16x8 a = *reinterpret_cast<const bf16x8*>(
                &AN[r][0] + (((kk * 4 + lg) ^ (r & 7)) << 3));
            acc[m] = __builtin_amdgcn_mfma_f32_16x16x32_bf16(a, b, acc[m], 0, 0, 0);
        }
    }
    #pragma unroll
    for (int m = 0; m < 4; ++m) {
        #pragma unroll
        for (int q = 0; q < 4; ++q) {
            const int r = m * 16 + lg * 4 + q;
            HN[r][mycol ^ ((r & 7) << 3)] = f2bf(silu_f(acc[m][q] + bn1_l));
        }
    }
    __syncthreads();

    f32x4 acc2[4] = {z4, z4, z4, z4};
    #pragma unroll
    for (int kk = 0; kk < 4; ++kk) {
        const bf16x8 b = *reinterpret_cast<const bf16x8*>(wtn2 + mycol * 128 + kk * 32 + lg * 8);
        #pragma unroll
        for (int m = 0; m < 4; ++m) {
            const int r = m * 16 + lr;
            const bf16x8 a = *reinterpret_cast<const bf16x8*>(
                &HN[r][0] + (((kk * 4 + lg) ^ (r & 7)) << 3));
            acc2[m] = __builtin_amdgcn_mfma_f32_16x16x32_bf16(a, b, acc2[m], 0, 0, 0);
        }
    }
    #pragma unroll
    for (int m = 0; m < 4; ++m) {
        #pragma unroll
        for (int q = 0; q < 4; ++q) {
            const int n = n0 + m * 16 + lg * 4 + q;
            if (n < NN) outx[(size_t)n * HIDC + mycol] = acc2[m][q] + bn2_l;
        }
    }
    if (tid < 192) {
        const int r = n0 + tid / 3;
        const int d2 = tid - (tid / 3) * 3;
        if (r < NN) outp[r * 3 + d2] = pos[r * 3 + d2] + cagg[r * 3 + d2];
    }
}

// ---------------- launch ----------------
extern "C" void kernel_launch(void* const* d_in, const int* in_sizes, int n_in,
                              void* d_out, int out_size, void* d_ws, size_t ws_size,
                              hipStream_t stream)
{
    const float* x   = (const float*)d_in[0];
    const float* pos = (const float*)d_in[1];
    const int*   ei  = (const int*)d_in[2];
    const float* ea  = (const float*)d_in[3];
    const float* Wm1 = (const float*)d_in[4];
    const float* bm1 = (const float*)d_in[5];
    const float* Wm2 = (const float*)d_in[6];
    const float* bm2 = (const float*)d_in[7];
    const float* Wn1 = (const float*)d_in[8];
    const float* bn1 = (const float*)d_in[9];
    const float* Wn2 = (const float*)d_in[10];
    const float* bn2 = (const float*)d_in[11];
    const float* Wc1 = (const float*)d_in[12];
    const float* bc1 = (const float*)d_in[13];
    const float* Wc2 = (const float*)d_in[14];
    const float* bc2 = (const float*)d_in[15];

    char* ws = (char*)d_ws;
    unsigned short* Pb   = (unsigned short*)(ws);              // 12,800,000
    unsigned short* Qb   = (unsigned short*)(ws + 12800000);   // 12,800,000
    float* agg           = (float*)(ws + 25600000);            // 25,600,000
    float* cagg          = (float*)(ws + 51200000);            //    600,000 (contiguous after agg)
    int*   cnt           = (int*)(ws + 51800000);              //    200,000
    int*   offs2         = (int*)(ws + 52000000);              //    200,000
    int*   part          = (int*)(ws + 52200000);              //      1,024
    int4*  epck          = (int4*)(ws + 52201024);             // 20,480,000
    unsigned short* wta  = (unsigned short*)(ws + 72681024);   //     32,768
    unsigned short* wtb  = (unsigned short*)(ws + 72713792);   //     32,768
    unsigned short* wt2  = (unsigned short*)(ws + 72746560);   //     32,768
    unsigned short* wtc1 = (unsigned short*)(ws + 72779328);   //     32,768
    unsigned short* wtn1 = (unsigned short*)(ws + 72812096);   //     65,536
    unsigned short* wtn2 = (unsigned short*)(ws + 72877632);   //     32,768

    float* outx = (float*)d_out;
    float* outp = outx + (size_t)NN * HIDC;

    hipMemsetAsync(cnt, 0, NN * sizeof(int), stream);
    convw_count_kernel<<<448 + 2500, 256, 0, stream>>>(Wm1, Wm2, Wc1, Wn1, Wn2, ei,
                                                       wta, wtb, wt2, wtc1, wtn1, wtn2, cnt);
    scanA_kernel<<<250, 256, 0, stream>>>(cnt, part);
    scanB_kernel<<<1, 64, 0, stream>>>(part);
    scanC_kernel<<<250, 256, 0, stream>>>(cnt, part, offs2);
    scatter_kernel<<<2500, 256, 0, stream>>>(ei, pos, ea, offs2, epck);
    pq_kernel<<<NTILES + 200, 512, 0, stream>>>(x, wta, wtb, bm1, Pb, Qb, agg);
    edge_kernel<<<256, 1024, 0, stream>>>(Pb, Qb, epck, wt2, wtc1, Wm1,
                                          bm2, bc1, Wc2, bc2, agg, cagg);
    node_kernel<<<NTILES, 512, 0, stream>>>(x, agg, cagg, wtn1, wtn2, bn1, bn2,
                                            pos, outx, outp);
}

// Round 12
// 233.400 us; speedup vs baseline: 1.3842x; 1.0494x over previous
//
#include <hip/hip_runtime.h>
#include <math.h>

#define NN 50000
#define NE 640000
#define HIDC 128
#define NTILES ((NN + 63)/64)

typedef short  short8 __attribute__((ext_vector_type(8)));
typedef __bf16 bf16x8 __attribute__((ext_vector_type(8)));
typedef float  f32x4  __attribute__((ext_vector_type(4)));
typedef unsigned int uint2v __attribute__((ext_vector_type(2)));
typedef unsigned int uint4v __attribute__((ext_vector_type(4)));

__device__ __forceinline__ unsigned short f2bf(float f) {
    unsigned int b = __float_as_uint(f);
    b += 0x7FFFu + ((b >> 16) & 1u);          // RTNE
    return (unsigned short)(b >> 16);
}
// silu via v_rcp (1 op) instead of IEEE div (~10 ops). ~1ulp, invisible at bf16.
__device__ __forceinline__ float silu_f(float v) {
    return v * __builtin_amdgcn_rcpf(1.0f + __expf(-v));
}
// packed RTNE f32->bf16 pair (1 VALU op)
__device__ __forceinline__ unsigned int cvtpk(float a, float b) {
    unsigned int r;
    asm("v_cvt_pk_bf16_f32 %0, %1, %2" : "=v"(r) : "v"(a), "v"(b));
    return r;
}

// ---------------- merged prep: weight transposes + degree count ----------------
__global__ void convw_count_kernel(const float* __restrict__ Wm1, const float* __restrict__ Wm2,
                                   const float* __restrict__ Wc1, const float* __restrict__ Wn1,
                                   const float* __restrict__ Wn2, const int* __restrict__ ei,
                                   unsigned short* __restrict__ wta, unsigned short* __restrict__ wtb,
                                   unsigned short* __restrict__ wt2, unsigned short* __restrict__ wtc1,
                                   unsigned short* __restrict__ wtn1, unsigned short* __restrict__ wtn2,
                                   int* __restrict__ cnt) {
    if (blockIdx.x >= 448) {   // count part
        const int e = (blockIdx.x - 448) * 256 + threadIdx.x;
        if (e < NE) atomicAdd(&cnt[ei[e]], 1);
        return;
    }
    const int i = blockIdx.x * 256 + threadIdx.x;
    if (i < 16384) {
        const int n = i >> 7, k = i & 127;
        wta[i] = f2bf(Wm1[k * 128 + n]);
    } else if (i < 32768) {
        const int j = i - 16384; const int n = j >> 7, k = j & 127;
        wtb[j] = f2bf(Wm1[(128 + k) * 128 + n]);
    } else if (i < 49152) {
        const int j = i - 32768; const int n = j >> 7, k = j & 127;
        wt2[j] = f2bf(Wm2[k * 128 + n]);
    } else if (i < 65536) {
        const int j = i - 49152; const int n = j >> 7, k = j & 127;
        wtc1[j] = f2bf(Wc1[k * 128 + n]);
    } else if (i < 98304) {
        const int j = i - 65536; const int n = j >> 8, k = j & 255;
        wtn1[j] = f2bf(Wn1[k * 128 + n]);
    } else if (i < 114688) {
        const int j = i - 98304; const int n = j >> 7, k = j & 127;
        wtn2[j] = f2bf(Wn2[k * 128 + n]);
    }
}

// ---------------- CSR scan (parallel 3-kernel chain) ----------------
__global__ void scanA_kernel(const int* __restrict__ cnt, int* __restrict__ part) {
    __shared__ int ws[4];
    const int t = threadIdx.x, b = blockIdx.x;
    int v = (t < 200) ? cnt[b * 200 + t] : 0;
    #pragma unroll
    for (int d2 = 1; d2 < 64; d2 <<= 1) v += __shfl_xor(v, d2, 64);
    if ((t & 63) == 0) ws[t >> 6] = v;
    __syncthreads();
    if (t == 0) part[b] = ws[0] + ws[1] + ws[2] + ws[3];
}

__global__ void scanB_kernel(int* __restrict__ part) {   // 1 block, 64 threads
    const int t = threadIdx.x;
    int v[4]; int tot = 0;
    #pragma unroll
    for (int i = 0; i < 4; ++i) {
        const int idx = t * 4 + i;
        v[i] = (idx < 250) ? part[idx] : 0;
        tot += v[i];
    }
    int incl = tot;
    #pragma unroll
    for (int d2 = 1; d2 < 64; d2 <<= 1) { int u = __shfl_up(incl, d2, 64); if (t >= d2) incl += u; }
    int ex = incl - tot;
    #pragma unroll
    for (int i = 0; i < 4; ++i) {
        const int idx = t * 4 + i;
        if (idx < 250) part[idx] = ex;
        ex += v[i];
    }
}

__global__ void scanC_kernel(const int* __restrict__ cnt, const int* __restrict__ part,
                             int* __restrict__ offs2) {
    __shared__ int wex[4];
    const int t = threadIdx.x, b = blockIdx.x;
    const int lane = t & 63, w = t >> 6;
    int v = (t < 200) ? cnt[b * 200 + t] : 0;
    int incl = v;
    #pragma unroll
    for (int d2 = 1; d2 < 64; d2 <<= 1) { int u = __shfl_up(incl, d2, 64); if (lane >= d2) incl += u; }
    if (lane == 63) wex[w] = incl;
    __syncthreads();
    if (t == 0) { int a = 0; for (int i = 0; i < 4; ++i) { int x = wex[i]; wex[i] = a; a += x; } }
    __syncthreads();
    if (t < 200) offs2[b * 200 + t] = incl - v + wex[w] + part[b];
}

// ---------------- fused scatter + P/Q precompute + agg/cagg zeroing ----------------
// Blocks [0,1250): scatter+pack (atomic/latency-bound).
// Blocks [1250,2032): pq MFMA (compute-bound) — co-resident overlap with scatter.
// Blocks [2032,2232): zero agg|cagg.
__launch_bounds__(512, 4)
__global__ void scatter_pq_kernel(const int* __restrict__ ei, const float* __restrict__ pos,
                                  const float* __restrict__ eattr,
                                  int* __restrict__ offs2, int4* __restrict__ epck,
                                  const float* __restrict__ x,
                                  const unsigned short* __restrict__ wta,
                                  const unsigned short* __restrict__ wtb,
                                  const float* __restrict__ bm1v,
                                  unsigned short* __restrict__ Pb, unsigned short* __restrict__ Qb,
                                  float* __restrict__ aggz)
{
    const int blk = blockIdx.x;
    if (blk < 1250) {   // ---- scatter: epck[slot] = {dx,dy,dz,dist | ea0,ea1,ea2, src|dst<<16}
        const int e = blk * 512 + threadIdx.x;
        if (e < NE) {
            const int s = ei[e], d = ei[NE + e];
            const int slot = atomicAdd(&offs2[s], 1);
            const float dx = pos[s*3+0] - pos[d*3+0];
            const float dy = pos[s*3+1] - pos[d*3+1];
            const float dz = pos[s*3+2] - pos[d*3+2];
            const float dist = sqrtf(dx*dx + dy*dy + dz*dz);
            int4 a, b;
            a.x = __float_as_int(dx); a.y = __float_as_int(dy);
            a.z = __float_as_int(dz); a.w = __float_as_int(dist);
            b.x = __float_as_int(eattr[e*3+0]); b.y = __float_as_int(eattr[e*3+1]);
            b.z = __float_as_int(eattr[e*3+2]); b.w = s | (d << 16);
            epck[(size_t)slot * 2 + 0] = a;
            epck[(size_t)slot * 2 + 1] = b;
        }
        return;
    }
    if (blk >= 2032) {  // ---- zero: agg (6.4M f32) + cagg (150k f32), contiguous
        const int zt = (blk - 2032) * 512 + threadIdx.x;   // 0..102399
        const f32x4 z4v = {0.f, 0.f, 0.f, 0.f};
        for (size_t i = zt; i < 1637500; i += 102400)
            *reinterpret_cast<f32x4*>(aggz + i * 4) = z4v;
        return;
    }
    // ---- pq: P = x*Wa + bm1, Q = x*Wb (bf16 tables)
    __shared__ __align__(16) unsigned short AN[64][128];
    const int tid = threadIdx.x;
    const int lane = tid & 63;
    const int wid = tid >> 6;
    const int lr = lane & 15;
    const int lg = lane >> 4;
    const int mycol = wid * 16 + lr;
    const float bm1_l = bm1v[mycol];
    const f32x4 z4 = {0.f, 0.f, 0.f, 0.f};
    const int n0 = (blk - 1250) * 64;

    {
        const int i = tid >> 3, j = tid & 7;
        const int n = n0 + i;
        const bool ok = (n < NN);
        #pragma unroll
        for (int gi = 0; gi < 2; ++gi) {
            const int g = j + gi * 8;
            short8 v = {0,0,0,0,0,0,0,0};
            if (ok) {
                const float* xp = x + (size_t)n * HIDC + (g << 3);
                const f32x4 a = *reinterpret_cast<const f32x4*>(xp);
                const f32x4 b = *reinterpret_cast<const f32x4*>(xp + 4);
                #pragma unroll
                for (int cc = 0; cc < 4; ++cc) { v[cc] = (short)f2bf(a[cc]); v[cc+4] = (short)f2bf(b[cc]); }
            }
            *reinterpret_cast<short8*>(&AN[i][0] + ((g ^ (i & 7)) << 3)) = v;
        }
    }
    __syncthreads();

    f32x4 accp[4] = {z4, z4, z4, z4};
    f32x4 accq[4] = {z4, z4, z4, z4};
    #pragma unroll
    for (int kk = 0; kk < 4; ++kk) {
        const bf16x8 ba = *reinterpret_cast<const bf16x8*>(wta + mycol * 128 + kk * 32 + lg * 8);
        const bf16x8 bb = *reinterpret_cast<const bf16x8*>(wtb + mycol * 128 + kk * 32 + lg * 8);
        #pragma unroll
        for (int m = 0; m < 4; ++m) {
            const int r = m * 16 + lr;
            const bf16x8 a = *reinterpret_cast<const bf16x8*>(
                &AN[r][0] + (((kk * 4 + lg) ^ (r & 7)) << 3));
            accp[m] = __builtin_amdgcn_mfma_f32_16x16x32_bf16(a, ba, accp[m], 0, 0, 0);
            accq[m] = __builtin_amdgcn_mfma_f32_16x16x32_bf16(a, bb, accq[m], 0, 0, 0);
        }
    }
    #pragma unroll
    for (int m = 0; m < 4; ++m) {
        #pragma unroll
        for (int q = 0; q < 4; ++q) {
            const int n = n0 + m * 16 + lg * 4 + q;
            if (n < NN) {
                Pb[(size_t)n * HIDC + mycol] = f2bf(accp[m][q] + bm1_l);
                Qb[(size_t)n * HIDC + mycol] = f2bf(accq[m][q]);
            }
        }
    }
}

// ---------------- edge kernel: zero barriers in loop, wave-owned 16-edge tiles ----------------
// Transposed GEMMs: A = weights (LDS), B = per-edge features (regs).
// D layout: col = lane&15 = edge, row = (lane>>4)*4+q (+16*mt) = hid.
// Cross-tile P/Q register prefetch; exp+rcp silu; explicit lgkmcnt fence before GEMM3
// (measured faster than compiler-managed: r8/r10 ~150us vs r11 ~154us without).
__launch_bounds__(1024, 4)
__global__ void edge_kernel(
    const unsigned short* __restrict__ Pb, const unsigned short* __restrict__ Qb,
    const int4* __restrict__ epck,
    const unsigned short* __restrict__ wt2g, const unsigned short* __restrict__ wtc1g,
    const float* __restrict__ Wm1,
    const float* __restrict__ bm2v, const float* __restrict__ bc1v,
    const float* __restrict__ wc2v, const float* __restrict__ bc2v,
    float* __restrict__ agg, float* __restrict__ cagg)
{
    __shared__ __align__(16) unsigned short wt2L[128][128];   // 32 KB
    __shared__ __align__(16) unsigned short wtc1L[128][128];  // 32 KB
    __shared__ __align__(16) float cons[4][128];              // bm2, bc1, wc2, -
    __shared__ __align__(16) float w4F[128][4];               // W1 rows 256..259 (f32), 2 KB
    __shared__ __align__(16) unsigned int MW[16][16 * 68];    // per-wave scratch, 68 KB

    const int tid = threadIdx.x;
    const int lane = tid & 63;
    const int wid = tid >> 6;

    // one-time fills (only barrier in the kernel)
    #pragma unroll
    for (int i = tid; i < 2048; i += 1024) {
        const int n = i >> 4, G = i & 15;
        *reinterpret_cast<short8*>(&wt2L[n][(G ^ (n & 7)) << 3]) =
            *reinterpret_cast<const short8*>(wt2g + n * 128 + G * 8);
    }
    #pragma unroll
    for (int i = tid; i < 2048; i += 1024) {
        const int n = i >> 4, G = i & 15;
        *reinterpret_cast<short8*>(&wtc1L[n][(G ^ (n & 7)) << 3]) =
            *reinterpret_cast<const short8*>(wtc1g + n * 128 + G * 8);
    }
    if (tid < 512) { const int h = tid >> 2, w = tid & 3; w4F[h][w] = Wm1[(256 + w) * 128 + h]; }
    if (tid < 384) {
        const int r = tid >> 7, j = tid & 127;
        cons[r][j] = (r == 0) ? bm2v[j] : (r == 1) ? bc1v[j] : wc2v[j];
    }
    __syncthreads();
    const float bc2s = bc2v[0];

    const int c = lane & 15, g = lane >> 4, c7 = c & 7;
    unsigned int* mw = &MW[wid][0];
    const f32x4 z4 = {0.f, 0.f, 0.f, 0.f};

    // balanced tile split over 4096 waves: 40000 = 3136*10 + 960*9
    const int gw = blockIdx.x * 16 + wid;    // 0..4095
    int t = gw * 9 + (gw < 3136 ? gw : 3136);
    const int tEnd = t + 9 + (gw < 3136 ? 1 : 0);

    int cur = -1; float s0a = 0.f, s1a = 0.f;      // cross-tile agg run accumulators

    auto flushA = [&]() {
        const float u1 = __shfl(s0a, lane >> 1, 64);
        const float v1 = __shfl(s1a, lane >> 1, 64);
        atomicAdd(&agg[(size_t)cur * HIDC + lane], (lane & 1) ? v1 : u1);
        const float u2 = __shfl(s0a, 32 + (lane >> 1), 64);
        const float v2 = __shfl(s1a, 32 + (lane >> 1), 64);
        atomicAdd(&agg[(size_t)cur * HIDC + 64 + lane], (lane & 1) ? v2 : u2);
    };

    int4 eA = epck[(size_t)(t * 16 + c) * 2 + 0];
    int4 eB = epck[(size_t)(t * 16 + c) * 2 + 1];

    // prime first tile's P/Q gathers
    bf16x8 Pf[4], Qf[4];
    {
        const int s0 = eB.w & 0xffff;
        const int d0 = ((unsigned)eB.w) >> 16;
        #pragma unroll
        for (int kk = 0; kk < 4; ++kk) {
            Pf[kk] = *reinterpret_cast<const bf16x8*>(Pb + (size_t)s0 * HIDC + kk * 32 + g * 8);
            Qf[kk] = *reinterpret_cast<const bf16x8*>(Qb + (size_t)d0 * HIDC + kk * 32 + g * 8);
        }
    }

    for (; t < tEnd; ++t) {
        const float dx = __int_as_float(eA.x);
        const float dy = __int_as_float(eA.y);
        const float dz = __int_as_float(eA.z);
        const float dist = __int_as_float(eA.w);
        const float ea0 = __int_as_float(eB.x);
        const float ea1 = __int_as_float(eB.y);
        const float ea2 = __int_as_float(eB.z);
        const int s = eB.w & 0xffff;
        const bool more = (t + 1 < tEnd);

        if (more) {   // prefetch next tile's edge data
            eA = epck[(size_t)((t + 1) * 16 + c) * 2 + 0];
            eB = epck[(size_t)((t + 1) * 16 + c) * 2 + 1];
        }

        // build h (per kk) and run GEMM2 immediately (consumes Pf/Qf)
        f32x4 acc2[8] = {z4, z4, z4, z4, z4, z4, z4, z4};
        #pragma unroll
        for (int kk = 0; kk < 4; ++kk) {
            const int hb = kk * 32 + g * 8;
            uint4v hw;
            #pragma unroll
            for (int jp = 0; jp < 4; ++jp) {
                float hv[2];
                #pragma unroll
                for (int u = 0; u < 2; ++u) {
                    const int j = 2 * jp + u;
                    const f32x4 w = *reinterpret_cast<const f32x4*>(&w4F[hb + j][0]);
                    const float hvv = (float)Pf[kk][j] + (float)Qf[kk][j]
                        + dist * w[0] + ea0 * w[1] + ea1 * w[2] + ea2 * w[3];
                    hv[u] = silu_f(hvv);
                }
                hw[jp] = cvtpk(hv[0], hv[1]);
            }
            const bf16x8 hf = *reinterpret_cast<const bf16x8*>(&hw);
            __builtin_amdgcn_s_setprio(1);
            #pragma unroll
            for (int mt = 0; mt < 8; ++mt) {
                const bf16x8 a = *reinterpret_cast<const bf16x8*>(
                    &wt2L[mt * 16 + c][(((kk << 2) + g) ^ c7) << 3]);
                acc2[mt] = __builtin_amdgcn_mfma_f32_16x16x32_bf16(a, hf, acc2[mt], 0, 0, 0);
            }
            __builtin_amdgcn_s_setprio(0);
        }

        // Pf/Qf now dead: issue NEXT tile's P/Q gathers (latency hides under the rest)
        if (more) {
            const int sN = eB.w & 0xffff;
            const int dN = ((unsigned)eB.w) >> 16;
            #pragma unroll
            for (int kk = 0; kk < 4; ++kk) {
                Pf[kk] = *reinterpret_cast<const bf16x8*>(Pb + (size_t)sN * HIDC + kk * 32 + g * 8);
                Qf[kk] = *reinterpret_cast<const bf16x8*>(Qb + (size_t)dN * HIDC + kk * 32 + g * 8);
            }
        }

        // epilogue: silu+bm2, pack msg pairs, write wave scratch
        #pragma unroll
        for (int mt = 0; mt < 8; ++mt) {
            const f32x4 bm2q = *reinterpret_cast<const f32x4*>(&cons[0][mt * 16 + 4 * g]);
            const unsigned int p0 = cvtpk(silu_f(acc2[mt][0] + bm2q[0]), silu_f(acc2[mt][1] + bm2q[1]));
            const unsigned int p1 = cvtpk(silu_f(acc2[mt][2] + bm2q[2]), silu_f(acc2[mt][3] + bm2q[3]));
            *reinterpret_cast<uint2v*>(&mw[c * 68 + 8 * mt + 2 * g]) = (uint2v){p0, p1};
        }
        asm volatile("s_waitcnt lgkmcnt(0)" ::: "memory");
        __builtin_amdgcn_sched_barrier(0);

        // GEMM3: t^T = Wc1 * msg^T
        f32x4 acc3[8] = {z4, z4, z4, z4, z4, z4, z4, z4};
        #pragma unroll
        for (int kk = 0; kk < 4; ++kk) {
            const bf16x8 bfr = *reinterpret_cast<const bf16x8*>(&mw[c * 68 + 16 * kk + 4 * g]);
            __builtin_amdgcn_s_setprio(1);
            #pragma unroll
            for (int mt = 0; mt < 8; ++mt) {
                const bf16x8 a = *reinterpret_cast<const bf16x8*>(
                    &wtc1L[mt * 16 + c][(((kk << 2) + g) ^ c7) << 3]);
                acc3[mt] = __builtin_amdgcn_mfma_f32_16x16x32_bf16(a, bfr, acc3[mt], 0, 0, 0);
            }
            __builtin_amdgcn_s_setprio(0);
        }

        // coord weight: cw = Wc2 . silu(t) + bc2, reduce over g-groups
        float cw = 0.f;
        #pragma unroll
        for (int mt = 0; mt < 8; ++mt) {
            const f32x4 bc1q = *reinterpret_cast<const f32x4*>(&cons[1][mt * 16 + 4 * g]);
            const f32x4 wc2q = *reinterpret_cast<const f32x4*>(&cons[2][mt * 16 + 4 * g]);
            #pragma unroll
            for (int q = 0; q < 4; ++q)
                cw += silu_f(acc3[mt][q] + bc1q[q]) * wc2q[q];
        }
        cw += __shfl_xor(cw, 16, 64);
        cw += __shfl_xor(cw, 32, 64);
        cw += bc2s;

        // coord: segmented inclusive scan over c (runs contiguous by src)
        float vx = dx * cw, vy = dy * cw, vz = dz * cw;
        #pragma unroll
        for (int dd = 1; dd < 16; dd <<= 1) {
            const int su = __shfl_up(s, dd, 16);
            const float ux = __shfl_up(vx, dd, 16);
            const float uy = __shfl_up(vy, dd, 16);
            const float uz = __shfl_up(vz, dd, 16);
            if (c >= dd && su == s) { vx += ux; vy += uy; vz += uz; }
        }
        {
            const int sdn = __shfl_down(s, 1, 16);
            if (g == 0 && (c == 15 || sdn != s)) {
                atomicAdd(&cagg[s * 3 + 0], vx);
                atomicAdd(&cagg[s * 3 + 1], vy);
                atomicAdd(&cagg[s * 3 + 2], vz);
            }
        }

        // serial segmented column-sum over the 16 edges (runs carried across tiles),
        // LDS reads batched in chunks of 8 to amortize latency
        #pragma unroll
        for (int eh = 0; eh < 2; ++eh) {
            unsigned int rv8[8];
            #pragma unroll
            for (int e = 0; e < 8; ++e) rv8[e] = mw[(eh * 8 + e) * 68 + lane];
            #pragma unroll
            for (int e = 0; e < 8; ++e) {
                const int se = __builtin_amdgcn_readlane(s, eh * 8 + e);
                const float f0 = __uint_as_float(rv8[e] << 16);
                const float f1 = __uint_as_float(rv8[e] & 0xffff0000u);
                if (se != cur) {
                    if (cur >= 0) flushA();
                    cur = se; s0a = f0; s1a = f1;
                } else { s0a += f0; s1a += f1; }
            }
        }
    }
    if (cur >= 0) flushA();
}

// ---------------- node kernel: node MLP + pos_new ----------------
__launch_bounds__(512, 4)
__global__ void node_kernel(
    const float* __restrict__ x, const float* __restrict__ agg,
    const float* __restrict__ cagg,
    const unsigned short* __restrict__ wtn1, const unsigned short* __restrict__ wtn2,
    const float* __restrict__ bn1v, const float* __restrict__ bn2v,
    const float* __restrict__ pos,
    float* __restrict__ outx, float* __restrict__ outp)
{
    __shared__ __align__(16) unsigned short AN[64][256];
    __shared__ __align__(16) unsigned short HN[64][HIDC];
    const int tid = threadIdx.x;
    const int lane = tid & 63;
    const int wid = tid >> 6;
    const int lr = lane & 15;
    const int lg = lane >> 4;
    const int mycol = wid * 16 + lr;
    const float bn1_l = bn1v[mycol];
    const float bn2_l = bn2v[mycol];
    const f32x4 z4 = {0.f, 0.f, 0.f, 0.f};
    const int n0 = blockIdx.x * 64;

    {
        const int i = tid >> 3, j = tid & 7;
        const int n = n0 + i;
        const bool ok = (n < NN);
        #pragma unroll
        for (int gi = 0; gi < 4; ++gi) {
            const int g = j + gi * 8;                      // 0..31
            short8 v = {0,0,0,0,0,0,0,0};
            if (ok) {
                const float* sp = (g < 16) ? (x + (size_t)n * HIDC + (g << 3))
                                           : (agg + (size_t)n * HIDC + ((g - 16) << 3));
                const f32x4 a = *reinterpret_cast<const f32x4*>(sp);
                const f32x4 b = *reinterpret_cast<const f32x4*>(sp + 4);
                #pragma unroll
                for (int cc = 0; cc < 4; ++cc) { v[cc] = (short)f2bf(a[cc]); v[cc+4] = (short)f2bf(b[cc]); }
            }
            *reinterpret_cast<short8*>(&AN[i][0] + ((g ^ (i & 7)) << 3)) = v;
        }
    }
    __syncthreads();

    f32x4 acc[4] = {z4, z4, z4, z4};
    #pragma unroll
    for (int kk = 0; kk < 8; ++kk) {
        const bf16x8 b = *reinterpret_cast<const bf16x8*>(wtn1 + mycol * 256 + kk * 32 + lg * 8);
        #pragma unroll
        for (int m = 0; m < 4; ++m) {
            const int r = m * 16 + lr;
            const bf16x8 a = *reinterpret_cast<const bf16x8*>(
                &AN[r][0] + (((kk * 4 + lg) ^ (r & 7)) << 3));
            acc[m] = __builtin_amdgcn_mfma_f32_16x16x32_bf16(a, b, acc[m], 0, 0, 0);
        }
    }
    #pragma unroll
    for (int m = 0; m < 4; ++m) {
        #pragma unroll
        for (int q = 0; q < 4; ++q) {
            const int r = m * 16 + lg * 4 + q;
            HN[r][mycol ^ ((r & 7) << 3)] = f2bf(silu_f(acc[m][q] + bn1_l));
        }
    }
    __syncthreads();

    f32x4 acc2[4] = {z4, z4, z4, z4};
    #pragma unroll
    for (int kk = 0; kk < 4; ++kk) {
        const bf16x8 b = *reinterpret_cast<const bf16x8*>(wtn2 + mycol * 128 + kk * 32 + lg * 8);
        #pragma unroll
        for (int m = 0; m < 4; ++m) {
            const int r = m * 16 + lr;
            const bf16x8 a = *reinterpret_cast<const bf16x8*>(
                &HN[r][0] + (((kk * 4 + lg) ^ (r & 7)) << 3));
            acc2[m] = __builtin_amdgcn_mfma_f32_16x16x32_bf16(a, b, acc2[m], 0, 0, 0);
        }
    }
    #pragma unroll
    for (int m = 0; m < 4; ++m) {
        #pragma unroll
        for (int q = 0; q < 4; ++q) {
            const int n = n0 + m * 16 + lg * 4 + q;
            if (n < NN) outx[(size_t)n * HIDC + mycol] = acc2[m][q] + bn2_l;
        }
    }
    if (tid < 192) {
        const int r = n0 + tid / 3;
        const int d2 = tid - (tid / 3) * 3;
        if (r < NN) outp[r * 3 + d2] = pos[r * 3 + d2] + cagg[r * 3 + d2];
    }
}

// ---------------- launch ----------------
extern "C" void kernel_launch(void* const* d_in, const int* in_sizes, int n_in,
                              void* d_out, int out_size, void* d_ws, size_t ws_size,
                              hipStream_t stream)
{
    const float* x   = (const float*)d_in[0];
    const float* pos = (const float*)d_in[1];
    const int*   ei  = (const int*)d_in[2];
    const float* ea  = (const float*)d_in[3];
    const float* Wm1 = (const float*)d_in[4];
    const float* bm1 = (const float*)d_in[5];
    const float* Wm2 = (const float*)d_in[6];
    const float* bm2 = (const float*)d_in[7];
    const float* Wn1 = (const float*)d_in[8];
    const float* bn1 = (const float*)d_in[9];
    const float* Wn2 = (const float*)d_in[10];
    const float* bn2 = (const float*)d_in[11];
    const float* Wc1 = (const float*)d_in[12];
    const float* bc1 = (const float*)d_in[13];
    const float* Wc2 = (const float*)d_in[14];
    const float* bc2 = (const float*)d_in[15];

    char* ws = (char*)d_ws;
    unsigned short* Pb   = (unsigned short*)(ws);              // 12,800,000
    unsigned short* Qb   = (unsigned short*)(ws + 12800000);   // 12,800,000
    float* agg           = (float*)(ws + 25600000);            // 25,600,000
    float* cagg          = (float*)(ws + 51200000);            //    600,000 (contiguous after agg)
    int*   cnt           = (int*)(ws + 51800000);              //    200,000
    int*   offs2         = (int*)(ws + 52000000);              //    200,000
    int*   part          = (int*)(ws + 52200000);              //      1,024
    int4*  epck          = (int4*)(ws + 52201024);             // 20,480,000
    unsigned short* wta  = (unsigned short*)(ws + 72681024);   //     32,768
    unsigned short* wtb  = (unsigned short*)(ws + 72713792);   //     32,768
    unsigned short* wt2  = (unsigned short*)(ws + 72746560);   //     32,768
    unsigned short* wtc1 = (unsigned short*)(ws + 72779328);   //     32,768
    unsigned short* wtn1 = (unsigned short*)(ws + 72812096);   //     65,536
    unsigned short* wtn2 = (unsigned short*)(ws + 72877632);   //     32,768

    float* outx = (float*)d_out;
    float* outp = outx + (size_t)NN * HIDC;

    hipMemsetAsync(cnt, 0, NN * sizeof(int), stream);
    convw_count_kernel<<<448 + 2500, 256, 0, stream>>>(Wm1, Wm2, Wc1, Wn1, Wn2, ei,
                                                       wta, wtb, wt2, wtc1, wtn1, wtn2, cnt);
    scanA_kernel<<<250, 256, 0, stream>>>(cnt, part);
    scanB_kernel<<<1, 64, 0, stream>>>(part);
    scanC_kernel<<<250, 256, 0, stream>>>(cnt, part, offs2);
    scatter_pq_kernel<<<2232, 512, 0, stream>>>(ei, pos, ea, offs2, epck,
                                                x, wta, wtb, bm1, Pb, Qb, agg);
    edge_kernel<<<256, 1024, 0, stream>>>(Pb, Qb, epck, wt2, wtc1, Wm1,
                                          bm2, bc1, Wc2, bc2, agg, cagg);
    node_kernel<<<NTILES, 512, 0, stream>>>(x, agg, cagg, wtn1, wtn2, bn1, bn2,
                                            pos, outx, outp);
}

// Round 13
// 231.042 us; speedup vs baseline: 1.3984x; 1.0102x over previous
//
#include <hip/hip_runtime.h>
#include <math.h>

#define NN 50000
#define NE 640000
#define HIDC 128
#define NTILES ((NN + 63)/64)

typedef short  short8 __attribute__((ext_vector_type(8)));
typedef __bf16 bf16x8 __attribute__((ext_vector_type(8)));
typedef float  f32x4  __attribute__((ext_vector_type(4)));
typedef unsigned int uint2v __attribute__((ext_vector_type(2)));
typedef unsigned int uint4v __attribute__((ext_vector_type(4)));

__device__ __forceinline__ unsigned short f2bf(float f) {
    unsigned int b = __float_as_uint(f);
    b += 0x7FFFu + ((b >> 16) & 1u);          // RTNE
    return (unsigned short)(b >> 16);
}
// silu via v_rcp (1 op) instead of IEEE div (~10 ops). ~1ulp, invisible at bf16.
__device__ __forceinline__ float silu_f(float v) {
    return v * __builtin_amdgcn_rcpf(1.0f + __expf(-v));
}
// packed RTNE f32->bf16 pair (1 VALU op)
__device__ __forceinline__ unsigned int cvtpk(float a, float b) {
    unsigned int r;
    asm("v_cvt_pk_bf16_f32 %0, %1, %2" : "=v"(r) : "v"(a), "v"(b));
    return r;
}

// ---------------- merged prep: weight transposes + degree count ----------------
__global__ void convw_count_kernel(const float* __restrict__ Wm1, const float* __restrict__ Wm2,
                                   const float* __restrict__ Wc1, const float* __restrict__ Wn1,
                                   const float* __restrict__ Wn2, const int* __restrict__ ei,
                                   unsigned short* __restrict__ wta, unsigned short* __restrict__ wtb,
                                   unsigned short* __restrict__ wt2, unsigned short* __restrict__ wtc1,
                                   unsigned short* __restrict__ wtn1, unsigned short* __restrict__ wtn2,
                                   int* __restrict__ cnt) {
    if (blockIdx.x >= 448) {   // count part
        const int e = (blockIdx.x - 448) * 256 + threadIdx.x;
        if (e < NE) atomicAdd(&cnt[ei[e]], 1);
        return;
    }
    const int i = blockIdx.x * 256 + threadIdx.x;
    if (i < 16384) {
        const int n = i >> 7, k = i & 127;
        wta[i] = f2bf(Wm1[k * 128 + n]);
    } else if (i < 32768) {
        const int j = i - 16384; const int n = j >> 7, k = j & 127;
        wtb[j] = f2bf(Wm1[(128 + k) * 128 + n]);
    } else if (i < 49152) {
        const int j = i - 32768; const int n = j >> 7, k = j & 127;
        wt2[j] = f2bf(Wm2[k * 128 + n]);
    } else if (i < 65536) {
        const int j = i - 49152; const int n = j >> 7, k = j & 127;
        wtc1[j] = f2bf(Wc1[k * 128 + n]);
    } else if (i < 98304) {
        const int j = i - 65536; const int n = j >> 8, k = j & 255;
        wtn1[j] = f2bf(Wn1[k * 128 + n]);
    } else if (i < 114688) {
        const int j = i - 98304; const int n = j >> 7, k = j & 127;
        wtn2[j] = f2bf(Wn2[k * 128 + n]);
    }
}

// ---------------- CSR scan: scanA (per-chunk sums) + scanC (prefix + local scan) ----------------
__global__ void scanA_kernel(const int* __restrict__ cnt, int* __restrict__ part) {
    __shared__ int ws[4];
    const int t = threadIdx.x, b = blockIdx.x;
    int v = (t < 200) ? cnt[b * 200 + t] : 0;
    #pragma unroll
    for (int d2 = 1; d2 < 64; d2 <<= 1) v += __shfl_xor(v, d2, 64);
    if ((t & 63) == 0) ws[t >> 6] = v;
    __syncthreads();
    if (t == 0) part[b] = ws[0] + ws[1] + ws[2] + ws[3];
}

// scanC with scanB folded in: each block redundantly reduces part[0..b-1] (250 ints).
__global__ void scanC_kernel(const int* __restrict__ cnt, const int* __restrict__ part,
                             int* __restrict__ offs2) {
    __shared__ int pw[4];
    __shared__ int wex[4];
    __shared__ int basep;
    const int t = threadIdx.x, b = blockIdx.x;
    const int lane = t & 63, w = t >> 6;
    // exclusive base = sum part[0..b-1]
    int pv = (t < b) ? part[t] : 0;            // b <= 249 < 256
    #pragma unroll
    for (int d2 = 1; d2 < 64; d2 <<= 1) pv += __shfl_xor(pv, d2, 64);
    if (lane == 0) pw[w] = pv;
    __syncthreads();
    if (t == 0) basep = pw[0] + pw[1] + pw[2] + pw[3];
    // local scan of this chunk's 200 counts
    int v = (t < 200) ? cnt[b * 200 + t] : 0;
    int incl = v;
    #pragma unroll
    for (int d2 = 1; d2 < 64; d2 <<= 1) { int u = __shfl_up(incl, d2, 64); if (lane >= d2) incl += u; }
    if (lane == 63) wex[w] = incl;
    __syncthreads();
    if (t == 0) { int a = 0; for (int i = 0; i < 4; ++i) { int x = wex[i]; wex[i] = a; a += x; } }
    __syncthreads();
    if (t < 200) offs2[b * 200 + t] = incl - v + wex[w] + basep;
}

// ---------------- fused scatter + P/Q precompute + agg/cagg zeroing ----------------
// Blocks [0,1250): scatter+pack (atomic/latency-bound).
// Blocks [1250,2032): pq MFMA (compute-bound) — co-resident overlap with scatter.
// Blocks [2032,2232): zero agg|cagg.
__launch_bounds__(512, 4)
__global__ void scatter_pq_kernel(const int* __restrict__ ei, const float* __restrict__ pos,
                                  const float* __restrict__ eattr,
                                  int* __restrict__ offs2, int4* __restrict__ epck,
                                  const float* __restrict__ x,
                                  const unsigned short* __restrict__ wta,
                                  const unsigned short* __restrict__ wtb,
                                  const float* __restrict__ bm1v,
                                  unsigned short* __restrict__ Pb, unsigned short* __restrict__ Qb,
                                  float* __restrict__ aggz)
{
    const int blk = blockIdx.x;
    if (blk < 1250) {   // ---- scatter: epck[slot] = {dx,dy,dz,dist | ea0,ea1,ea2, src|dst<<16}
        const int e = blk * 512 + threadIdx.x;
        if (e < NE) {
            const int s = ei[e], d = ei[NE + e];
            const int slot = atomicAdd(&offs2[s], 1);
            const float dx = pos[s*3+0] - pos[d*3+0];
            const float dy = pos[s*3+1] - pos[d*3+1];
            const float dz = pos[s*3+2] - pos[d*3+2];
            const float dist = sqrtf(dx*dx + dy*dy + dz*dz);
            int4 a, b;
            a.x = __float_as_int(dx); a.y = __float_as_int(dy);
            a.z = __float_as_int(dz); a.w = __float_as_int(dist);
            b.x = __float_as_int(eattr[e*3+0]); b.y = __float_as_int(eattr[e*3+1]);
            b.z = __float_as_int(eattr[e*3+2]); b.w = s | (d << 16);
            epck[(size_t)slot * 2 + 0] = a;
            epck[(size_t)slot * 2 + 1] = b;
        }
        return;
    }
    if (blk >= 2032) {  // ---- zero: agg (6.4M f32) + cagg (150k f32), contiguous
        const int zt = (blk - 2032) * 512 + threadIdx.x;   // 0..102399
        const f32x4 z4v = {0.f, 0.f, 0.f, 0.f};
        for (size_t i = zt; i < 1637500; i += 102400)
            *reinterpret_cast<f32x4*>(aggz + i * 4) = z4v;
        return;
    }
    // ---- pq: P = x*Wa + bm1, Q = x*Wb (bf16 tables)
    __shared__ __align__(16) unsigned short AN[64][128];
    const int tid = threadIdx.x;
    const int lane = tid & 63;
    const int wid = tid >> 6;
    const int lr = lane & 15;
    const int lg = lane >> 4;
    const int mycol = wid * 16 + lr;
    const float bm1_l = bm1v[mycol];
    const f32x4 z4 = {0.f, 0.f, 0.f, 0.f};
    const int n0 = (blk - 1250) * 64;

    {
        const int i = tid >> 3, j = tid & 7;
        const int n = n0 + i;
        const bool ok = (n < NN);
        #pragma unroll
        for (int gi = 0; gi < 2; ++gi) {
            const int g = j + gi * 8;
            short8 v = {0,0,0,0,0,0,0,0};
            if (ok) {
                const float* xp = x + (size_t)n * HIDC + (g << 3);
                const f32x4 a = *reinterpret_cast<const f32x4*>(xp);
                const f32x4 b = *reinterpret_cast<const f32x4*>(xp + 4);
                #pragma unroll
                for (int cc = 0; cc < 4; ++cc) { v[cc] = (short)f2bf(a[cc]); v[cc+4] = (short)f2bf(b[cc]); }
            }
            *reinterpret_cast<short8*>(&AN[i][0] + ((g ^ (i & 7)) << 3)) = v;
        }
    }
    __syncthreads();

    f32x4 accp[4] = {z4, z4, z4, z4};
    f32x4 accq[4] = {z4, z4, z4, z4};
    #pragma unroll
    for (int kk = 0; kk < 4; ++kk) {
        const bf16x8 ba = *reinterpret_cast<const bf16x8*>(wta + mycol * 128 + kk * 32 + lg * 8);
        const bf16x8 bb = *reinterpret_cast<const bf16x8*>(wtb + mycol * 128 + kk * 32 + lg * 8);
        #pragma unroll
        for (int m = 0; m < 4; ++m) {
            const int r = m * 16 + lr;
            const bf16x8 a = *reinterpret_cast<const bf16x8*>(
                &AN[r][0] + (((kk * 4 + lg) ^ (r & 7)) << 3));
            accp[m] = __builtin_amdgcn_mfma_f32_16x16x32_bf16(a, ba, accp[m], 0, 0, 0);
            accq[m] = __builtin_amdgcn_mfma_f32_16x16x32_bf16(a, bb, accq[m], 0, 0, 0);
        }
    }
    #pragma unroll
    for (int m = 0; m < 4; ++m) {
        #pragma unroll
        for (int q = 0; q < 4; ++q) {
            const int n = n0 + m * 16 + lg * 4 + q;
            if (n < NN) {
                Pb[(size_t)n * HIDC + mycol] = f2bf(accp[m][q] + bm1_l);
                Qb[(size_t)n * HIDC + mycol] = f2bf(accq[m][q]);
            }
        }
    }
}

// ---------------- edge kernel: zero barriers in loop, wave-owned 16-edge tiles ----------------
// Transposed GEMMs: A = weights (LDS), B = per-edge features (regs).
// D layout: col = lane&15 = edge, row = (lane>>4)*4+q (+16*mt) = hid.
// Cross-tile P/Q register prefetch; exp+rcp silu; explicit lgkmcnt fence before GEMM3
// (measured faster than compiler-managed: r8/r10 ~150us vs r11 ~154us without).
// FROZEN at round-12 best-measured config.
__launch_bounds__(1024, 4)
__global__ void edge_kernel(
    const unsigned short* __restrict__ Pb, const unsigned short* __restrict__ Qb,
    const int4* __restrict__ epck,
    const unsigned short* __restrict__ wt2g, const unsigned short* __restrict__ wtc1g,
    const float* __restrict__ Wm1,
    const float* __restrict__ bm2v, const float* __restrict__ bc1v,
    const float* __restrict__ wc2v, const float* __restrict__ bc2v,
    float* __restrict__ agg, float* __restrict__ cagg)
{
    __shared__ __align__(16) unsigned short wt2L[128][128];   // 32 KB
    __shared__ __align__(16) unsigned short wtc1L[128][128];  // 32 KB
    __shared__ __align__(16) float cons[4][128];              // bm2, bc1, wc2, -
    __shared__ __align__(16) float w4F[128][4];               // W1 rows 256..259 (f32), 2 KB
    __shared__ __align__(16) unsigned int MW[16][16 * 68];    // per-wave scratch, 68 KB

    const int tid = threadIdx.x;
    const int lane = tid & 63;
    const int wid = tid >> 6;

    // one-time fills (only barrier in the kernel)
    #pragma unroll
    for (int i = tid; i < 2048; i += 1024) {
        const int n = i >> 4, G = i & 15;
        *reinterpret_cast<short8*>(&wt2L[n][(G ^ (n & 7)) << 3]) =
            *reinterpret_cast<const short8*>(wt2g + n * 128 + G * 8);
    }
    #pragma unroll
    for (int i = tid; i < 2048; i += 1024) {
        const int n = i >> 4, G = i & 15;
        *reinterpret_cast<short8*>(&wtc1L[n][(G ^ (n & 7)) << 3]) =
            *reinterpret_cast<const short8*>(wtc1g + n * 128 + G * 8);
    }
    if (tid < 512) { const int h = tid >> 2, w = tid & 3; w4F[h][w] = Wm1[(256 + w) * 128 + h]; }
    if (tid < 384) {
        const int r = tid >> 7, j = tid & 127;
        cons[r][j] = (r == 0) ? bm2v[j] : (r == 1) ? bc1v[j] : wc2v[j];
    }
    __syncthreads();
    const float bc2s = bc2v[0];

    const int c = lane & 15, g = lane >> 4, c7 = c & 7;
    unsigned int* mw = &MW[wid][0];
    const f32x4 z4 = {0.f, 0.f, 0.f, 0.f};

    // balanced tile split over 4096 waves: 40000 = 3136*10 + 960*9
    const int gw = blockIdx.x * 16 + wid;    // 0..4095
    int t = gw * 9 + (gw < 3136 ? gw : 3136);
    const int tEnd = t + 9 + (gw < 3136 ? 1 : 0);

    int cur = -1; float s0a = 0.f, s1a = 0.f;      // cross-tile agg run accumulators

    auto flushA = [&]() {
        const float u1 = __shfl(s0a, lane >> 1, 64);
        const float v1 = __shfl(s1a, lane >> 1, 64);
        atomicAdd(&agg[(size_t)cur * HIDC + lane], (lane & 1) ? v1 : u1);
        const float u2 = __shfl(s0a, 32 + (lane >> 1), 64);
        const float v2 = __shfl(s1a, 32 + (lane >> 1), 64);
        atomicAdd(&agg[(size_t)cur * HIDC + 64 + lane], (lane & 1) ? v2 : u2);
    };

    int4 eA = epck[(size_t)(t * 16 + c) * 2 + 0];
    int4 eB = epck[(size_t)(t * 16 + c) * 2 + 1];

    // prime first tile's P/Q gathers
    bf16x8 Pf[4], Qf[4];
    {
        const int s0 = eB.w & 0xffff;
        const int d0 = ((unsigned)eB.w) >> 16;
        #pragma unroll
        for (int kk = 0; kk < 4; ++kk) {
            Pf[kk] = *reinterpret_cast<const bf16x8*>(Pb + (size_t)s0 * HIDC + kk * 32 + g * 8);
            Qf[kk] = *reinterpret_cast<const bf16x8*>(Qb + (size_t)d0 * HIDC + kk * 32 + g * 8);
        }
    }

    for (; t < tEnd; ++t) {
        const float dx = __int_as_float(eA.x);
        const float dy = __int_as_float(eA.y);
        const float dz = __int_as_float(eA.z);
        const float dist = __int_as_float(eA.w);
        const float ea0 = __int_as_float(eB.x);
        const float ea1 = __int_as_float(eB.y);
        const float ea2 = __int_as_float(eB.z);
        const int s = eB.w & 0xffff;
        const bool more = (t + 1 < tEnd);

        if (more) {   // prefetch next tile's edge data
            eA = epck[(size_t)((t + 1) * 16 + c) * 2 + 0];
            eB = epck[(size_t)((t + 1) * 16 + c) * 2 + 1];
        }

        // build h (per kk) and run GEMM2 immediately (consumes Pf/Qf)
        f32x4 acc2[8] = {z4, z4, z4, z4, z4, z4, z4, z4};
        #pragma unroll
        for (int kk = 0; kk < 4; ++kk) {
            const int hb = kk * 32 + g * 8;
            uint4v hw;
            #pragma unroll
            for (int jp = 0; jp < 4; ++jp) {
                float hv[2];
                #pragma unroll
                for (int u = 0; u < 2; ++u) {
                    const int j = 2 * jp + u;
                    const f32x4 w = *reinterpret_cast<const f32x4*>(&w4F[hb + j][0]);
                    const float hvv = (float)Pf[kk][j] + (float)Qf[kk][j]
                        + dist * w[0] + ea0 * w[1] + ea1 * w[2] + ea2 * w[3];
                    hv[u] = silu_f(hvv);
                }
                hw[jp] = cvtpk(hv[0], hv[1]);
            }
            const bf16x8 hf = *reinterpret_cast<const bf16x8*>(&hw);
            __builtin_amdgcn_s_setprio(1);
            #pragma unroll
            for (int mt = 0; mt < 8; ++mt) {
                const bf16x8 a = *reinterpret_cast<const bf16x8*>(
                    &wt2L[mt * 16 + c][(((kk << 2) + g) ^ c7) << 3]);
                acc2[mt] = __builtin_amdgcn_mfma_f32_16x16x32_bf16(a, hf, acc2[mt], 0, 0, 0);
            }
            __builtin_amdgcn_s_setprio(0);
        }

        // Pf/Qf now dead: issue NEXT tile's P/Q gathers (latency hides under the rest)
        if (more) {
            const int sN = eB.w & 0xffff;
            const int dN = ((unsigned)eB.w) >> 16;
            #pragma unroll
            for (int kk = 0; kk < 4; ++kk) {
                Pf[kk] = *reinterpret_cast<const bf16x8*>(Pb + (size_t)sN * HIDC + kk * 32 + g * 8);
                Qf[kk] = *reinterpret_cast<const bf16x8*>(Qb + (size_t)dN * HIDC + kk * 32 + g * 8);
            }
        }

        // epilogue: silu+bm2, pack msg pairs, write wave scratch
        #pragma unroll
        for (int mt = 0; mt < 8; ++mt) {
            const f32x4 bm2q = *reinterpret_cast<const f32x4*>(&cons[0][mt * 16 + 4 * g]);
            const unsigned int p0 = cvtpk(silu_f(acc2[mt][0] + bm2q[0]), silu_f(acc2[mt][1] + bm2q[1]));
            const unsigned int p1 = cvtpk(silu_f(acc2[mt][2] + bm2q[2]), silu_f(acc2[mt][3] + bm2q[3]));
            *reinterpret_cast<uint2v*>(&mw[c * 68 + 8 * mt + 2 * g]) = (uint2v){p0, p1};
        }
        asm volatile("s_waitcnt lgkmcnt(0)" ::: "memory");
        __builtin_amdgcn_sched_barrier(0);

        // GEMM3: t^T = Wc1 * msg^T
        f32x4 acc3[8] = {z4, z4, z4, z4, z4, z4, z4, z4};
        #pragma unroll
        for (int kk = 0; kk < 4; ++kk) {
            const bf16x8 bfr = *reinterpret_cast<const bf16x8*>(&mw[c * 68 + 16 * kk + 4 * g]);
            __builtin_amdgcn_s_setprio(1);
            #pragma unroll
            for (int mt = 0; mt < 8; ++mt) {
                const bf16x8 a = *reinterpret_cast<const bf16x8*>(
                    &wtc1L[mt * 16 + c][(((kk << 2) + g) ^ c7) << 3]);
                acc3[mt] = __builtin_amdgcn_mfma_f32_16x16x32_bf16(a, bfr, acc3[mt], 0, 0, 0);
            }
            __builtin_amdgcn_s_setprio(0);
        }

        // coord weight: cw = Wc2 . silu(t) + bc2, reduce over g-groups
        float cw = 0.f;
        #pragma unroll
        for (int mt = 0; mt < 8; ++mt) {
            const f32x4 bc1q = *reinterpret_cast<const f32x4*>(&cons[1][mt * 16 + 4 * g]);
            const f32x4 wc2q = *reinterpret_cast<const f32x4*>(&cons[2][mt * 16 + 4 * g]);
            #pragma unroll
            for (int q = 0; q < 4; ++q)
                cw += silu_f(acc3[mt][q] + bc1q[q]) * wc2q[q];
        }
        cw += __shfl_xor(cw, 16, 64);
        cw += __shfl_xor(cw, 32, 64);
        cw += bc2s;

        // coord: segmented inclusive scan over c (runs contiguous by src)
        float vx = dx * cw, vy = dy * cw, vz = dz * cw;
        #pragma unroll
        for (int dd = 1; dd < 16; dd <<= 1) {
            const int su = __shfl_up(s, dd, 16);
            const float ux = __shfl_up(vx, dd, 16);
            const float uy = __shfl_up(vy, dd, 16);
            const float uz = __shfl_up(vz, dd, 16);
            if (c >= dd && su == s) { vx += ux; vy += uy; vz += uz; }
        }
        {
            const int sdn = __shfl_down(s, 1, 16);
            if (g == 0 && (c == 15 || sdn != s)) {
                atomicAdd(&cagg[s * 3 + 0], vx);
                atomicAdd(&cagg[s * 3 + 1], vy);
                atomicAdd(&cagg[s * 3 + 2], vz);
            }
        }

        // serial segmented column-sum over the 16 edges (runs carried across tiles),
        // LDS reads batched in chunks of 8 to amortize latency
        #pragma unroll
        for (int eh = 0; eh < 2; ++eh) {
            unsigned int rv8[8];
            #pragma unroll
            for (int e = 0; e < 8; ++e) rv8[e] = mw[(eh * 8 + e) * 68 + lane];
            #pragma unroll
            for (int e = 0; e < 8; ++e) {
                const int se = __builtin_amdgcn_readlane(s, eh * 8 + e);
                const float f0 = __uint_as_float(rv8[e] << 16);
                const float f1 = __uint_as_float(rv8[e] & 0xffff0000u);
                if (se != cur) {
                    if (cur >= 0) flushA();
                    cur = se; s0a = f0; s1a = f1;
                } else { s0a += f0; s1a += f1; }
            }
        }
    }
    if (cur >= 0) flushA();
}

// ---------------- node kernel: node MLP + pos_new ----------------
__launch_bounds__(512, 4)
__global__ void node_kernel(
    const float* __restrict__ x, const float* __restrict__ agg,
    const float* __restrict__ cagg,
    const unsigned short* __restrict__ wtn1, const unsigned short* __restrict__ wtn2,
    const float* __restrict__ bn1v, const float* __restrict__ bn2v,
    const float* __restrict__ pos,
    float* __restrict__ outx, float* __restrict__ outp)
{
    __shared__ __align__(16) unsigned short AN[64][256];
    __shared__ __align__(16) unsigned short HN[64][HIDC];
    const int tid = threadIdx.x;
    const int lane = tid & 63;
    const int wid = tid >> 6;
    const int lr = lane & 15;
    const int lg = lane >> 4;
    const int mycol = wid * 16 + lr;
    const float bn1_l = bn1v[mycol];
    const float bn2_l = bn2v[mycol];
    const f32x4 z4 = {0.f, 0.f, 0.f, 0.f};
    const int n0 = blockIdx.x * 64;

    {
        const int i = tid >> 3, j = tid & 7;
        const int n = n0 + i;
        const bool ok = (n < NN);
        #pragma unroll
        for (int gi = 0; gi < 4; ++gi) {
            const int g = j + gi * 8;                      // 0..31
            short8 v = {0,0,0,0,0,0,0,0};
            if (ok) {
                const float* sp = (g < 16) ? (x + (size_t)n * HIDC + (g << 3))
                                           : (agg + (size_t)n * HIDC + ((g - 16) << 3));
                const f32x4 a = *reinterpret_cast<const f32x4*>(sp);
                const f32x4 b = *reinterpret_cast<const f32x4*>(sp + 4);
                #pragma unroll
                for (int cc = 0; cc < 4; ++cc) { v[cc] = (short)f2bf(a[cc]); v[cc+4] = (short)f2bf(b[cc]); }
            }
            *reinterpret_cast<short8*>(&AN[i][0] + ((g ^ (i & 7)) << 3)) = v;
        }
    }
    __syncthreads();

    f32x4 acc[4] = {z4, z4, z4, z4};
    #pragma unroll
    for (int kk = 0; kk < 8; ++kk) {
        const bf16x8 b = *reinterpret_cast<const bf16x8*>(wtn1 + mycol * 256 + kk * 32 + lg * 8);
        #pragma unroll
        for (int m = 0; m < 4; ++m) {
            const int r = m * 16 + lr;
            const bf16x8 a = *reinterpret_cast<const bf16x8*>(
                &AN[r][0] + (((kk * 4 + lg) ^ (r & 7)) << 3));
            acc[m] = __builtin_amdgcn_mfma_f32_16x16x32_bf16(a, b, acc[m], 0, 0, 0);
        }
    }
    #pragma unroll
    for (int m = 0; m < 4; ++m) {
        #pragma unroll
        for (int q = 0; q < 4; ++q) {
            const int r = m * 16 + lg * 4 + q;
            HN[r][mycol ^ ((r & 7) << 3)] = f2bf(silu_f(acc[m][q] + bn1_l));
        }
    }
    __syncthreads();

    f32x4 acc2[4] = {z4, z4, z4, z4};
    #pragma unroll
    for (int kk = 0; kk < 4; ++kk) {
        const bf16x8 b = *reinterpret_cast<const bf16x8*>(wtn2 + mycol * 128 + kk * 32 + lg * 8);
        #pragma unroll
        for (int m = 0; m < 4; ++m) {
            const int r = m * 16 + lr;
            const bf16x8 a = *reinterpret_cast<const bf16x8*>(
                &HN[r][0] + (((kk * 4 + lg) ^ (r & 7)) << 3));
            acc2[m] = __builtin_amdgcn_mfma_f32_16x16x32_bf16(a, b, acc2[m], 0, 0, 0);
        }
    }
    #pragma unroll
    for (int m = 0; m < 4; ++m) {
        #pragma unroll
        for (int q = 0; q < 4; ++q) {
            const int n = n0 + m * 16 + lg * 4 + q;
            if (n < NN) outx[(size_t)n * HIDC + mycol] = acc2[m][q] + bn2_l;
        }
    }
    if (tid < 192) {
        const int r = n0 + tid / 3;
        const int d2 = tid - (tid / 3) * 3;
        if (r < NN) outp[r * 3 + d2] = pos[r * 3 + d2] + cagg[r * 3 + d2];
    }
}

// ---------------- launch ----------------
extern "C" void kernel_launch(void* const* d_in, const int* in_sizes, int n_in,
                              void* d_out, int out_size, void* d_ws, size_t ws_size,
                              hipStream_t stream)
{
    const float* x   = (const float*)d_in[0];
    const float* pos = (const float*)d_in[1];
    const int*   ei  = (const int*)d_in[2];
    const float* ea  = (const float*)d_in[3];
    const float* Wm1 = (const float*)d_in[4];
    const float* bm1 = (const float*)d_in[5];
    const float* Wm2 = (const float*)d_in[6];
    const float* bm2 = (const float*)d_in[7];
    const float* Wn1 = (const float*)d_in[8];
    const float* bn1 = (const float*)d_in[9];
    const float* Wn2 = (const float*)d_in[10];
    const float* bn2 = (const float*)d_in[11];
    const float* Wc1 = (const float*)d_in[12];
    const float* bc1 = (const float*)d_in[13];
    const float* Wc2 = (const float*)d_in[14];
    const float* bc2 = (const float*)d_in[15];

    char* ws = (char*)d_ws;
    unsigned short* Pb   = (unsigned short*)(ws);              // 12,800,000
    unsigned short* Qb   = (unsigned short*)(ws + 12800000);   // 12,800,000
    float* agg           = (float*)(ws + 25600000);            // 25,600,000
    float* cagg          = (float*)(ws + 51200000);            //    600,000 (contiguous after agg)
    int*   cnt           = (int*)(ws + 51800000);              //    200,000
    int*   offs2         = (int*)(ws + 52000000);              //    200,000
    int*   part          = (int*)(ws + 52200000);              //      1,024
    int4*  epck          = (int4*)(ws + 52201024);             // 20,480,000
    unsigned short* wta  = (unsigned short*)(ws + 72681024);   //     32,768
    unsigned short* wtb  = (unsigned short*)(ws + 72713792);   //     32,768
    unsigned short* wt2  = (unsigned short*)(ws + 72746560);   //     32,768
    unsigned short* wtc1 = (unsigned short*)(ws + 72779328);   //     32,768
    unsigned short* wtn1 = (unsigned short*)(ws + 72812096);   //     65,536
    unsigned short* wtn2 = (unsigned short*)(ws + 72877632);   //     32,768

    float* outx = (float*)d_out;
    float* outp = outx + (size_t)NN * HIDC;

    hipMemsetAsync(cnt, 0, NN * sizeof(int), stream);
    convw_count_kernel<<<448 + 2500, 256, 0, stream>>>(Wm1, Wm2, Wc1, Wn1, Wn2, ei,
                                                       wta, wtb, wt2, wtc1, wtn1, wtn2, cnt);
    scanA_kernel<<<250, 256, 0, stream>>>(cnt, part);
    scanC_kernel<<<250, 256, 0, stream>>>(cnt, part, offs2);
    scatter_pq_kernel<<<2232, 512, 0, stream>>>(ei, pos, ea, offs2, epck,
                                                x, wta, wtb, bm1, Pb, Qb, agg);
    edge_kernel<<<256, 1024, 0, stream>>>(Pb, Qb, epck, wt2, wtc1, Wm1,
                                          bm2, bc1, Wc2, bc2, agg, cagg);
    node_kernel<<<NTILES, 512, 0, stream>>>(x, agg, cagg, wtn1, wtn2, bn1, bn2,
                                            pos, outx, outp);
}